// Round 6
// baseline (2359.451 us; speedup 1.0000x reference)
//
#include <hip/hip_runtime.h>
#include <stdint.h>

// SPIRiT CG reconstruction. Convs via bf16 hi/lo-split MFMA (3 products:
// Wh*Xh + Wl*Xh + Wh*Xl), per-tap implicit GEMM: M=16 c_out, N=16 pixels,
// K=32 = 16 c_in x {re,im}. Fields are planar complex float2 f[c][384*384].
// Conv kernel: 512 threads (8 waves) per 16x16 tile, stage-once 24x24 slab,
// 81 taps. Weight ring (3 taps, global->reg) + X-fragment prefetch (LDS->reg).
// Raw s_barrier every 3 taps keeps waves tap-synced so the 8 duplicate
// weight streams coalesce in L1/MSHR (one L2 fetch per tap per CU).

#define MM 384
#define NPIX (MM*MM)          // 147456
#define N2 (16*NPIX)
#define NRED 512
#define NCBLK 576             // 24 x 24 tiles of 16x16 pixels

typedef __attribute__((ext_vector_type(8))) short short8;
typedef __attribute__((ext_vector_type(4))) float f32x4;
typedef unsigned int u32;

__device__ __forceinline__ float2 block_reduce2(float2 v) {
    #pragma unroll
    for (int off = 32; off > 0; off >>= 1) {
        v.x += __shfl_down(v.x, off);
        v.y += __shfl_down(v.y, off);
    }
    __shared__ float2 tmp[8];
    const int wid = threadIdx.x >> 6, lid = threadIdx.x & 63;
    if (lid == 0) tmp[wid] = v;
    __syncthreads();
    if (threadIdx.x == 0) {
        const int nw = blockDim.x >> 6;
        for (int i = 1; i < nw; ++i) { v.x += tmp[i].x; v.y += tmp[i].y; }
    }
    return v;
}

__device__ __forceinline__ void split_pair(float a, float b, u32& hw, u32& lw) {
    const u32 ua = __float_as_uint(a), ub = __float_as_uint(b);
    const u32 ha = ua & 0xFFFF0000u, hb = ub & 0xFFFF0000u;
    const float la = a - __uint_as_float(ha);
    const float lb = b - __uint_as_float(hb);
    hw = hb | (ha >> 16);
    lw = (__float_as_uint(lb) & 0xFFFF0000u) | (__float_as_uint(la) >> 16);
}

// Weight fragments: [dir][tap=p*9+q][pt(hi/lo)][hf][lane64][4 u32]
// A_half0[co][kc] = [Wr | -Wi], A_half1 = [Wi | Wr]; lane = co + 16*kgroup.
__global__ void prep_weights(const float* __restrict__ kr, const float* __restrict__ ki,
                             u32* __restrict__ wbuf) {
    const int e = blockIdx.x * 256 + threadIdx.x;
    if (e >= 20736) return;
    const int lane = e & 63;
    int r = e >> 6;
    const int hf = r & 1; r >>= 1;
    const int q = r % 9; r /= 9;
    const int p = r % 9; r /= 9;
    const int dir = r;
    const int co = lane & 15, g = lane >> 4;
    float vv[8];
    #pragma unroll
    for (int t = 0; t < 8; ++t) {
        const int kc = 8 * g + t;
        const int ci = kc & 15;
        const int isI = kc >> 4;
        int sidx;
        if (dir == 0) sidx = (q*9 + p)*256 + ci*16 + co;          // Wf[co,ci,p,q]=K[q,p,ci,co]
        else          sidx = ((8-q)*9 + (8-p))*256 + co*16 + ci;  // Wb = conj flip swap
        const float wr = kr[sidx];
        const float wi = (dir == 0) ? ki[sidx] : -ki[sidx];
        vv[t] = (hf == 0) ? (isI ? -wi : wr) : (isI ? wr : wi);
    }
    u32 hw[4], lw[4];
    #pragma unroll
    for (int t = 0; t < 4; ++t) split_pair(vv[2*t], vv[2*t+1], hw[t], lw[t]);
    const int b0 = dir*324 + (p*9 + q)*4 + hf;
    u32* o0 = wbuf + (size_t)b0*256 + lane*4;
    u32* o1 = o0 + 2*256;
    *(uint4*)o0 = make_uint4(hw[0], hw[1], hw[2], hw[3]);
    *(uint4*)o1 = make_uint4(lw[0], lw[1], lw[2], lw[3]);
}

__global__ void prep_fields(const float* __restrict__ ks, const float* __restrict__ prev,
                            float2* __restrict__ wsf, uint8_t* __restrict__ mask8) {
    const int pix = blockIdx.x * blockDim.x + threadIdx.x;
    if (pix >= NPIX) return;
    #pragma unroll
    for (int c = 0; c < 16; ++c) {
        const float krr = ks[(size_t)pix*32 + c];
        const float kii = ks[(size_t)pix*32 + c + 16];
        mask8[(size_t)c*NPIX + pix] = (krr != 0.f || kii != 0.f) ? 1 : 0;
        wsf[(size_t)c*NPIX + pix] = make_float2(prev[(size_t)pix*32 + c], prev[(size_t)pix*32 + c + 16]);
    }
}

// MODE 0: out = conv(x) - x
// MODE 1: out = conv(x) - x + (mask+am)*aux ; partial += out*conj(aux)
// MODE 2: out=out2 = mask*kk + am*z - (conv(x)-x) - (mask+am)*aux ; partial += |out|^2
template<int MODE>
__global__ __launch_bounds__(512)
void conv9(const float2* __restrict__ x, const u32* __restrict__ Wd,
           float2* __restrict__ out, float2* __restrict__ out2,
           const float2* __restrict__ aux, const float* __restrict__ ks,
           const float* __restrict__ z, const uint8_t* __restrict__ mask8,
           const float* __restrict__ miu, float2* __restrict__ partials)
{
    __shared__ __align__(16) char Xs[24*24*128];   // 73728 B
    const int t = threadIdx.x;
    const int bi = blockIdx.x;
    const int i0 = (bi / 24) * 16;
    const int j0 = (bi % 24) * 16;
    const int w = t >> 6, lane = t & 63;
    const int m = lane & 15, g = lane >> 4;

    // ---- stage the full 24x24 slab once (rows i0-4..i0+19, cols j0-4..j0+19)
    for (int u = t; u < 24*24*2; u += 512) {
        const int col = u % 24;
        const int cih = (u / 24) & 1;
        const int row = u / 48;
        const int row_g = i0 - 4 + row;
        const int col_g = j0 - 4 + col;
        const bool valid = ((unsigned)row_g < MM) && ((unsigned)col_g < MM);
        float2 v[8];
        const float2* src = x + (size_t)(cih*8)*NPIX + (size_t)row_g*MM + col_g;
        #pragma unroll
        for (int e = 0; e < 8; ++e)
            v[e] = valid ? src[(size_t)e*NPIX] : make_float2(0.f, 0.f);
        u32 reh[4], rel[4], imh[4], iml[4];
        #pragma unroll
        for (int k2 = 0; k2 < 4; ++k2) {
            split_pair(v[2*k2].x, v[2*k2+1].x, reh[k2], rel[k2]);
            split_pair(v[2*k2].y, v[2*k2+1].y, imh[k2], iml[k2]);
        }
        const int c7 = (col + 4) & 7;    // == col_g & 7 (j0 % 8 == 0)
        char* pb = Xs + (size_t)(row*24 + col)*128;
        *(uint4*)(pb + (((0 + cih) ^ c7) << 4)) = make_uint4(reh[0], reh[1], reh[2], reh[3]);
        *(uint4*)(pb + (((2 + cih) ^ c7) << 4)) = make_uint4(imh[0], imh[1], imh[2], imh[3]);
        *(uint4*)(pb + (((4 + cih) ^ c7) << 4)) = make_uint4(rel[0], rel[1], rel[2], rel[3]);
        *(uint4*)(pb + (((6 + cih) ^ c7) << 4)) = make_uint4(iml[0], iml[1], iml[2], iml[3]);
    }
    __syncthreads();

    f32x4 acc[2][2];
    #pragma unroll
    for (int a = 0; a < 2; ++a)
        #pragma unroll
        for (int h = 0; h < 2; ++h) acc[a][h] = (f32x4){0.f, 0.f, 0.f, 0.f};

    // ---- 81 taps. Weight ring: WA/WB/WC (3 taps deep, global->reg).
    //      X fragments: XA/XB (1 tap ahead, LDS->reg).
    //      Raw s_barrier every 3 taps: keeps the 8 waves' identical weight
    //      loads time-clustered -> L1/MSHR coalescing, one L2 fetch per tap.
    const char* wlp = (const char*)Wd + (lane << 4);
    short8 WA[4], WB[4], WC[4], XA[4], XB[4];
    char* xptr = Xs + (size_t)((2*w)*24 + m)*128;   // tap (p=0,q=0) base for this wave
    int qn = 0;                                      // q of tap being loaded next
    int c7n = (m + 4) & 7;                           // swizzle key of that tap

    // XN[0]/[1]: hi frags grp0/grp1 ; XN[2]/[3]: lo frags grp0/grp1
    #define LOADX(XN) do {                                                   \
        const int sw0_ = ((g ^ c7n) << 4);                                   \
        const int sw1_ = (((4 + g) ^ c7n) << 4);                             \
        XN[0] = *(const short8*)(xptr + sw0_);                               \
        XN[1] = *(const short8*)(xptr + 3072 + sw0_);                        \
        XN[2] = *(const short8*)(xptr + sw1_);                               \
        XN[3] = *(const short8*)(xptr + 3072 + sw1_);                        \
        const bool wr_ = (qn == 8);                                          \
        xptr += wr_ ? 2048 : 128;                                            \
        qn   = wr_ ? 0 : qn + 1;                                             \
        c7n  = wr_ ? c7n : ((c7n + 1) & 7);                                  \
    } while (0)

    #define LOADW(WS, OFF) do {                                              \
        WS[0] = *(const short8*)(wlp + (OFF));                               \
        WS[1] = *(const short8*)(wlp + (OFF) + 1024);                        \
        WS[2] = *(const short8*)(wlp + (OFF) + 2048);                        \
        WS[3] = *(const short8*)(wlp + (OFF) + 3072);                        \
    } while (0)

    // interleaved: 4 independent acc chains, dep distance 4
    #define MFMAS(XC, WS) do {                                               \
        acc[0][0] = __builtin_amdgcn_mfma_f32_16x16x32_bf16(WS[0], XC[0], acc[0][0], 0, 0, 0); \
        acc[1][0] = __builtin_amdgcn_mfma_f32_16x16x32_bf16(WS[0], XC[1], acc[1][0], 0, 0, 0); \
        acc[0][1] = __builtin_amdgcn_mfma_f32_16x16x32_bf16(WS[1], XC[0], acc[0][1], 0, 0, 0); \
        acc[1][1] = __builtin_amdgcn_mfma_f32_16x16x32_bf16(WS[1], XC[1], acc[1][1], 0, 0, 0); \
        acc[0][0] = __builtin_amdgcn_mfma_f32_16x16x32_bf16(WS[2], XC[0], acc[0][0], 0, 0, 0); \
        acc[1][0] = __builtin_amdgcn_mfma_f32_16x16x32_bf16(WS[2], XC[1], acc[1][0], 0, 0, 0); \
        acc[0][1] = __builtin_amdgcn_mfma_f32_16x16x32_bf16(WS[3], XC[0], acc[0][1], 0, 0, 0); \
        acc[1][1] = __builtin_amdgcn_mfma_f32_16x16x32_bf16(WS[3], XC[1], acc[1][1], 0, 0, 0); \
        acc[0][0] = __builtin_amdgcn_mfma_f32_16x16x32_bf16(WS[0], XC[2], acc[0][0], 0, 0, 0); \
        acc[1][0] = __builtin_amdgcn_mfma_f32_16x16x32_bf16(WS[0], XC[3], acc[1][0], 0, 0, 0); \
        acc[0][1] = __builtin_amdgcn_mfma_f32_16x16x32_bf16(WS[1], XC[2], acc[0][1], 0, 0, 0); \
        acc[1][1] = __builtin_amdgcn_mfma_f32_16x16x32_bf16(WS[1], XC[3], acc[1][1], 0, 0, 0); \
    } while (0)

    LOADW(WA, 0);          // tap 0
    LOADW(WB, 4096);       // tap 1
    LOADW(WC, 8192);       // tap 2
    wlp += 3*4096;         // wlp -> tap 3
    LOADX(XA);             // tap 0

    // taps 0..77, 13 x 6; ring slots A,B,C repeat; barrier after each triple
    #pragma unroll 1
    for (int it6 = 0; it6 < 13; ++it6) {
        LOADX(XB); MFMAS(XA, WA); LOADW(WA, 0);        // tap t   ; prefetch t+3
        LOADX(XA); MFMAS(XB, WB); LOADW(WB, 4096);     // tap t+1 ; prefetch t+4
        LOADX(XB); MFMAS(XA, WC); LOADW(WC, 8192);     // tap t+2 ; prefetch t+5
        __builtin_amdgcn_s_barrier();
        LOADX(XA); MFMAS(XB, WA); LOADW(WA, 12288);    // tap t+3 ; prefetch t+6
        LOADX(XB); MFMAS(XA, WB); LOADW(WB, 16384);    // tap t+4 ; prefetch t+7
        LOADX(XA); MFMAS(XB, WC); LOADW(WC, 20480);    // tap t+5 ; prefetch t+8
        __builtin_amdgcn_s_barrier();
        wlp += 6*4096;
    }
    // tail: taps 78 (WA, XA), 79 (WB), 80 (WC)
    LOADX(XB); MFMAS(XA, WA);   // tap 78
    LOADX(XA); MFMAS(XB, WB);   // tap 79
    MFMAS(XA, WC);              // tap 80

    #undef LOADX
    #undef LOADW
    #undef MFMAS

    // ---- epilogue: C/D col = lane&15 = pixel, row = g*4+j = co
    const float am = (MODE >= 1) ? fabsf(miu[0]) : 0.f;
    float2 part = make_float2(0.f, 0.f);
    #pragma unroll
    for (int grp = 0; grp < 2; ++grp) {
        const int rowo = i0 + 2*w + grp;
        const int colo = j0 + m;
        const int pix = rowo*MM + colo;
        #pragma unroll
        for (int j = 0; j < 4; ++j) {
            const int co = g*4 + j;
            const size_t idx = (size_t)co*NPIX + pix;
            const float rr = acc[grp][0][j], ii = acc[grp][1][j];
            if (MODE == 0) {
                const float2 xc = x[idx];
                out[idx] = make_float2(rr - xc.x, ii - xc.y);
            } else if (MODE == 1) {
                const float2 tc = x[idx];
                const float2 pc = aux[idx];
                const float mv = mask8[idx] ? 1.f : 0.f;
                const float qr = rr - tc.x + (mv + am)*pc.x;
                const float qi = ii - tc.y + (mv + am)*pc.y;
                out[idx] = make_float2(qr, qi);
                part.x += qr*pc.x + qi*pc.y;
                part.y += qi*pc.x - qr*pc.y;
            } else {
                const float2 tc = x[idx];
                const float2 wc = aux[idx];
                const float mv = mask8[idx] ? 1.f : 0.f;
                const float kr_ = ks[(size_t)pix*32 + co];
                const float ki_ = ks[(size_t)pix*32 + co + 16];
                const float zr  = z[(size_t)pix*32 + co];
                const float zi  = z[(size_t)pix*32 + co + 16];
                const float pr = mv*kr_ + am*zr - (rr - tc.x) - (mv + am)*wc.x;
                const float pi = mv*ki_ + am*zi - (ii - tc.y) - (mv + am)*wc.y;
                out[idx]  = make_float2(pr, pi);
                out2[idx] = make_float2(pr, pi);
                part.x += pr*pr + pi*pi;
            }
        }
    }
    if (MODE >= 1) {
        __syncthreads();
        part = block_reduce2(part);
        if (t == 0) partials[bi] = part;
    }
}

__global__ void finalize_rr(const float2* __restrict__ partials, float* __restrict__ scal, int n) {
    float2 s = make_float2(0.f, 0.f);
    for (int i = threadIdx.x; i < n; i += blockDim.x) { s.x += partials[i].x; s.y += partials[i].y; }
    s = block_reduce2(s);
    if (threadIdx.x == 0) scal[0] = s.x;
}

__global__ void finalize_alpha(const float2* __restrict__ partials, float* __restrict__ scal, int n) {
    float2 s = make_float2(0.f, 0.f);
    for (int i = threadIdx.x; i < n; i += blockDim.x) { s.x += partials[i].x; s.y += partials[i].y; }
    s = block_reduce2(s);
    if (threadIdx.x == 0) {
        const float rr = scal[0];
        const float d = s.x*s.x + s.y*s.y;
        scal[1] =  rr * s.x / d;
        scal[2] = -rr * s.y / d;
    }
}

__global__ void update_br(float2* __restrict__ b, const float2* __restrict__ p,
                          float2* __restrict__ r, const float2* __restrict__ q,
                          const float* __restrict__ scal, float2* __restrict__ partials) {
    const float ar = scal[1], ai = scal[2];
    float2 s = make_float2(0.f, 0.f);
    for (int e = blockIdx.x*256 + threadIdx.x; e < N2; e += NRED*256) {
        const float2 pv = p[e], qv = q[e];
        float2 bv = b[e], rv = r[e];
        bv.x += ar*pv.x - ai*pv.y;
        bv.y += ar*pv.y + ai*pv.x;
        rv.x -= ar*qv.x - ai*qv.y;
        rv.y -= ar*qv.y + ai*qv.x;
        b[e] = bv; r[e] = rv;
        s.x += rv.x*rv.x + rv.y*rv.y;
    }
    s = block_reduce2(s);
    if (threadIdx.x == 0) partials[blockIdx.x] = s;
}

__global__ void finalize_beta(const float2* __restrict__ partials, float* __restrict__ scal) {
    float2 v = partials[threadIdx.x];
    v = block_reduce2(v);
    if (threadIdx.x == 0) {
        const float rn = v.x;
        scal[3] = rn / scal[0];
        scal[0] = rn;
    }
}

__global__ void update_p(float2* __restrict__ p, const float2* __restrict__ r,
                         const float* __restrict__ scal) {
    const float beta = scal[3];
    const int e = blockIdx.x*256 + threadIdx.x;
    if (e < N2) {
        const float2 pv = p[e], rv = r[e];
        p[e] = make_float2(rv.x + beta*pv.x, rv.y + beta*pv.y);
    }
}

__global__ void pack_out(const float2* __restrict__ b, float* __restrict__ out) {
    const int e = blockIdx.x*256 + threadIdx.x;
    if (e >= 32*NPIX) return;
    const int pix = e >> 5;
    const int cc  = e & 31;
    const float2 v = b[(size_t)(cc & 15)*NPIX + pix];
    out[e] = (cc < 16) ? v.x : v.y;
}

extern "C" void kernel_launch(void* const* d_in, const int* in_sizes, int n_in,
                              void* d_out, int out_size, void* d_ws, size_t ws_size,
                              hipStream_t stream) {
    const float* z    = (const float*)d_in[0];
    const float* ks   = (const float*)d_in[1];
    const float* kr   = (const float*)d_in[2];
    const float* ki   = (const float*)d_in[3];
    const float* prev = (const float*)d_in[5];
    const float* miu  = (const float*)d_in[6];
    float* out = (float*)d_out;

    char* w = (char*)d_ws;
    const size_t FB = (size_t)N2 * sizeof(float2);
    float2* wsf = (float2*)w; w += FB;    // b (in-place)
    float2* pf  = (float2*)w; w += FB;
    float2* rf  = (float2*)w; w += FB;
    float2* qf  = (float2*)w; w += FB;
    float2* tf  = (float2*)w; w += FB;
    u32* wbuf   = (u32*)w;   w += (size_t)2*324*256*sizeof(u32);
    uint8_t* mask8 = (uint8_t*)w; w += (size_t)N2;
    w = (char*)(((uintptr_t)w + 255) & ~(uintptr_t)255);
    float2* partials = (float2*)w; w += (size_t)NCBLK * sizeof(float2);
    float*  scal     = (float*)w;

    const u32* wbF = wbuf;
    const u32* wbB = wbuf + (size_t)324*256;

    prep_weights<<<81, 256, 0, stream>>>(kr, ki, wbuf);
    prep_fields<<<576, 256, 0, stream>>>(ks, prev, wsf, mask8);

    conv9<0><<<NCBLK, 512, 0, stream>>>(wsf, wbF, tf, nullptr, nullptr, nullptr, nullptr, nullptr, nullptr, nullptr);
    conv9<2><<<NCBLK, 512, 0, stream>>>(tf, wbB, pf, rf, wsf, ks, z, mask8, miu, partials);
    finalize_rr<<<1, 256, 0, stream>>>(partials, scal, NCBLK);

    for (int it = 0; it < 10; ++it) {
        conv9<0><<<NCBLK, 512, 0, stream>>>(pf, wbF, tf, nullptr, nullptr, nullptr, nullptr, nullptr, nullptr, nullptr);
        conv9<1><<<NCBLK, 512, 0, stream>>>(tf, wbB, qf, nullptr, pf, nullptr, nullptr, mask8, miu, partials);
        finalize_alpha<<<1, 256, 0, stream>>>(partials, scal, NCBLK);
        update_br<<<NRED, 256, 0, stream>>>(wsf, pf, rf, qf, scal, partials);
        finalize_beta<<<1, NRED, 0, stream>>>(partials, scal);
        update_p<<<9216, 256, 0, stream>>>(pf, rf, scal);
    }

    pack_out<<<18432, 256, 0, stream>>>(wsf, out);
}

// Round 7
// 1683.339 us; speedup vs baseline: 1.4016x; 1.4016x over previous
//
#include <hip/hip_runtime.h>
#include <stdint.h>

// SPIRiT CG reconstruction. Convs via 2-product MFMA: W in RN-rounded bf16,
// X split hi/lo exactly (W*X ~= Wrn*Xh + Wrn*Xl). Per-tap implicit GEMM:
// M=16 c_out, N=16 pixels, K=32 = 16 c_in x {re,im}.
// Fields planar complex float2 f[c][384*384]. Conv kernel: 512 threads
// (8 waves) per 16x16 tile, stage-once 24x24 slab, 81 taps barrier-free,
// 3-tap weight register ring (global->reg, 2 frags/tap) + 1-tap X prefetch.

#define MM 384
#define NPIX (MM*MM)          // 147456
#define N2 (16*NPIX)
#define NRED 512
#define NCBLK 576             // 24 x 24 tiles of 16x16 pixels

typedef __attribute__((ext_vector_type(8))) short short8;
typedef __attribute__((ext_vector_type(4))) float f32x4;
typedef unsigned int u32;

__device__ __forceinline__ float2 block_reduce2(float2 v) {
    #pragma unroll
    for (int off = 32; off > 0; off >>= 1) {
        v.x += __shfl_down(v.x, off);
        v.y += __shfl_down(v.y, off);
    }
    __shared__ float2 tmp[8];
    const int wid = threadIdx.x >> 6, lid = threadIdx.x & 63;
    if (lid == 0) tmp[wid] = v;
    __syncthreads();
    if (threadIdx.x == 0) {
        const int nw = blockDim.x >> 6;
        for (int i = 1; i < nw; ++i) { v.x += tmp[i].x; v.y += tmp[i].y; }
    }
    return v;
}

// exact hi/lo split (hi = truncation, lo = exact remainder rounded)
__device__ __forceinline__ void split_pair(float a, float b, u32& hw, u32& lw) {
    const u32 ua = __float_as_uint(a), ub = __float_as_uint(b);
    const u32 ha = ua & 0xFFFF0000u, hb = ub & 0xFFFF0000u;
    const float la = a - __uint_as_float(ha);
    const float lb = b - __uint_as_float(hb);
    hw = hb | (ha >> 16);
    lw = (__float_as_uint(lb) & 0xFFFF0000u) | (__float_as_uint(la) >> 16);
}

__device__ __forceinline__ u32 bf16rn(float f) {   // round-to-nearest-even bf16
    const u32 u = __float_as_uint(f);
    return (u + 0x7FFFu + ((u >> 16) & 1u)) >> 16;
}

// Weight fragments (RN bf16, single level): [dir][tap=p*9+q][hf][lane64][4 u32]
// hf=0 rows: [Wr | -Wi] (-> rr), hf=1 rows: [Wi | Wr] (-> ii); lane = co + 16*kgroup.
// Tap block = 2 KB.
__global__ void prep_weights(const float* __restrict__ kr, const float* __restrict__ ki,
                             u32* __restrict__ wbuf) {
    const int e = blockIdx.x * 256 + threadIdx.x;
    if (e >= 20736) return;    // 2 dir x 81 tap x 2 hf x 64 lane
    const int lane = e & 63;
    int r = e >> 6;
    const int hf = r & 1; r >>= 1;
    const int q = r % 9; r /= 9;
    const int p = r % 9; r /= 9;
    const int dir = r;
    const int co = lane & 15, g = lane >> 4;
    float vv[8];
    #pragma unroll
    for (int t = 0; t < 8; ++t) {
        const int kc = 8 * g + t;
        const int ci = kc & 15;
        const int isI = kc >> 4;
        int sidx;
        if (dir == 0) sidx = (q*9 + p)*256 + ci*16 + co;          // Wf[co,ci,p,q]=K[q,p,ci,co]
        else          sidx = ((8-q)*9 + (8-p))*256 + co*16 + ci;  // Wb = conj flip swap
        const float wr = kr[sidx];
        const float wi = (dir == 0) ? ki[sidx] : -ki[sidx];
        vv[t] = (hf == 0) ? (isI ? -wi : wr) : (isI ? wr : wi);
    }
    u32 pk[4];
    #pragma unroll
    for (int t = 0; t < 4; ++t) pk[t] = bf16rn(vv[2*t]) | (bf16rn(vv[2*t+1]) << 16);
    u32* o = wbuf + (size_t)(dir*162 + (p*9 + q)*2 + hf)*256 + lane*4;
    *(uint4*)o = make_uint4(pk[0], pk[1], pk[2], pk[3]);
}

__global__ void prep_fields(const float* __restrict__ ks, const float* __restrict__ prev,
                            float2* __restrict__ wsf, uint8_t* __restrict__ mask8) {
    const int pix = blockIdx.x * blockDim.x + threadIdx.x;
    if (pix >= NPIX) return;
    #pragma unroll
    for (int c = 0; c < 16; ++c) {
        const float krr = ks[(size_t)pix*32 + c];
        const float kii = ks[(size_t)pix*32 + c + 16];
        mask8[(size_t)c*NPIX + pix] = (krr != 0.f || kii != 0.f) ? 1 : 0;
        wsf[(size_t)c*NPIX + pix] = make_float2(prev[(size_t)pix*32 + c], prev[(size_t)pix*32 + c + 16]);
    }
}

// MODE 0: out = conv(x) - x
// MODE 1: out = conv(x) - x + (mask+am)*aux ; partial += out*conj(aux)
// MODE 2: out=out2 = mask*kk + am*z - (conv(x)-x) - (mask+am)*aux ; partial += |out|^2
template<int MODE>
__global__ __launch_bounds__(512)
void conv9(const float2* __restrict__ x, const u32* __restrict__ Wd,
           float2* __restrict__ out, float2* __restrict__ out2,
           const float2* __restrict__ aux, const float* __restrict__ ks,
           const float* __restrict__ z, const uint8_t* __restrict__ mask8,
           const float* __restrict__ miu, float2* __restrict__ partials)
{
    __shared__ __align__(16) char Xs[24*24*128];   // 73728 B -> 2 blocks/CU
    const int t = threadIdx.x;
    const int bi = blockIdx.x;
    const int i0 = (bi / 24) * 16;
    const int j0 = (bi % 24) * 16;
    const int w = t >> 6, lane = t & 63;
    const int m = lane & 15, g = lane >> 4;

    // ---- stage the full 24x24 slab once (rows i0-4..i0+19, cols j0-4..j0+19)
    for (int u = t; u < 24*24*2; u += 512) {
        const int col = u % 24;
        const int cih = (u / 24) & 1;
        const int row = u / 48;
        const int row_g = i0 - 4 + row;
        const int col_g = j0 - 4 + col;
        const bool valid = ((unsigned)row_g < MM) && ((unsigned)col_g < MM);
        float2 v[8];
        const float2* src = x + (size_t)(cih*8)*NPIX + (size_t)row_g*MM + col_g;
        #pragma unroll
        for (int e = 0; e < 8; ++e)
            v[e] = valid ? src[(size_t)e*NPIX] : make_float2(0.f, 0.f);
        u32 reh[4], rel[4], imh[4], iml[4];
        #pragma unroll
        for (int k2 = 0; k2 < 4; ++k2) {
            split_pair(v[2*k2].x, v[2*k2+1].x, reh[k2], rel[k2]);
            split_pair(v[2*k2].y, v[2*k2+1].y, imh[k2], iml[k2]);
        }
        const int c7 = (col + 4) & 7;    // == col_g & 7 (j0 % 8 == 0)
        char* pb = Xs + (size_t)(row*24 + col)*128;
        *(uint4*)(pb + (((0 + cih) ^ c7) << 4)) = make_uint4(reh[0], reh[1], reh[2], reh[3]);
        *(uint4*)(pb + (((2 + cih) ^ c7) << 4)) = make_uint4(imh[0], imh[1], imh[2], imh[3]);
        *(uint4*)(pb + (((4 + cih) ^ c7) << 4)) = make_uint4(rel[0], rel[1], rel[2], rel[3]);
        *(uint4*)(pb + (((6 + cih) ^ c7) << 4)) = make_uint4(iml[0], iml[1], iml[2], iml[3]);
    }
    __syncthreads();

    f32x4 acc[2][2];
    #pragma unroll
    for (int a = 0; a < 2; ++a)
        #pragma unroll
        for (int h = 0; h < 2; ++h) acc[a][h] = (f32x4){0.f, 0.f, 0.f, 0.f};

    // ---- 81 taps. Weight ring: WA/WB/WC (3 taps deep, 2 frags/tap, global->reg).
    //      X fragments: XA/XB (1 tap ahead, LDS->reg).
    const char* wlp = (const char*)Wd + (lane << 4);
    short8 WA[2], WB[2], WC[2], XA[4], XB[4];
    char* xptr = Xs + (size_t)((2*w)*24 + m)*128;   // tap (p=0,q=0) base for this wave
    int qn = 0;                                      // q of tap being loaded next
    int c7n = (m + 4) & 7;                           // swizzle key of that tap

    // XN[0]/[1]: hi frags row0/row1 ; XN[2]/[3]: lo frags row0/row1
    #define LOADX(XN) do {                                                   \
        const int sw0_ = ((g ^ c7n) << 4);                                   \
        const int sw1_ = (((4 + g) ^ c7n) << 4);                             \
        XN[0] = *(const short8*)(xptr + sw0_);                               \
        XN[1] = *(const short8*)(xptr + 3072 + sw0_);                        \
        XN[2] = *(const short8*)(xptr + sw1_);                               \
        XN[3] = *(const short8*)(xptr + 3072 + sw1_);                        \
        const bool wr_ = (qn == 8);                                          \
        xptr += wr_ ? 2048 : 128;                                            \
        qn   = wr_ ? 0 : qn + 1;                                             \
        c7n  = wr_ ? c7n : ((c7n + 1) & 7);                                  \
    } while (0)

    #define LOADW(WS, OFF) do {                                              \
        WS[0] = *(const short8*)(wlp + (OFF));                               \
        WS[1] = *(const short8*)(wlp + (OFF) + 1024);                        \
    } while (0)

    // 8 MFMAs: 4 independent acc chains, dep distance 4
    #define MFMAS(XC, WS) do {                                               \
        acc[0][0] = __builtin_amdgcn_mfma_f32_16x16x32_bf16(WS[0], XC[0], acc[0][0], 0, 0, 0); \
        acc[1][0] = __builtin_amdgcn_mfma_f32_16x16x32_bf16(WS[0], XC[1], acc[1][0], 0, 0, 0); \
        acc[0][1] = __builtin_amdgcn_mfma_f32_16x16x32_bf16(WS[1], XC[0], acc[0][1], 0, 0, 0); \
        acc[1][1] = __builtin_amdgcn_mfma_f32_16x16x32_bf16(WS[1], XC[1], acc[1][1], 0, 0, 0); \
        acc[0][0] = __builtin_amdgcn_mfma_f32_16x16x32_bf16(WS[0], XC[2], acc[0][0], 0, 0, 0); \
        acc[1][0] = __builtin_amdgcn_mfma_f32_16x16x32_bf16(WS[0], XC[3], acc[1][0], 0, 0, 0); \
        acc[0][1] = __builtin_amdgcn_mfma_f32_16x16x32_bf16(WS[1], XC[2], acc[0][1], 0, 0, 0); \
        acc[1][1] = __builtin_amdgcn_mfma_f32_16x16x32_bf16(WS[1], XC[3], acc[1][1], 0, 0, 0); \
    } while (0)

    LOADW(WA, 0);          // tap 0
    LOADW(WB, 2048);       // tap 1
    LOADW(WC, 4096);       // tap 2
    wlp += 3*2048;         // wlp -> tap 3
    LOADX(XA);             // tap 0

    // taps 0..77, 13 x 6; ring slots A,B,C repeat
    #pragma unroll 1
    for (int it6 = 0; it6 < 13; ++it6) {
        LOADX(XB); MFMAS(XA, WA); LOADW(WA, 0);        // tap t   ; prefetch t+3
        LOADX(XA); MFMAS(XB, WB); LOADW(WB, 2048);     // tap t+1 ; prefetch t+4
        LOADX(XB); MFMAS(XA, WC); LOADW(WC, 4096);     // tap t+2 ; prefetch t+5
        LOADX(XA); MFMAS(XB, WA); LOADW(WA, 6144);     // tap t+3 ; prefetch t+6
        LOADX(XB); MFMAS(XA, WB); LOADW(WB, 8192);     // tap t+4 ; prefetch t+7
        LOADX(XA); MFMAS(XB, WC); LOADW(WC, 10240);    // tap t+5 ; prefetch t+8
        wlp += 6*2048;
    }
    // tail: taps 78 (WA, XA), 79 (WB), 80 (WC)
    LOADX(XB); MFMAS(XA, WA);   // tap 78
    LOADX(XA); MFMAS(XB, WB);   // tap 79
    MFMAS(XA, WC);              // tap 80

    #undef LOADX
    #undef LOADW
    #undef MFMAS

    // ---- epilogue: C/D col = lane&15 = pixel, row = g*4+j = co
    const float am = (MODE >= 1) ? fabsf(miu[0]) : 0.f;
    float2 part = make_float2(0.f, 0.f);
    #pragma unroll
    for (int grp = 0; grp < 2; ++grp) {
        const int rowo = i0 + 2*w + grp;
        const int colo = j0 + m;
        const int pix = rowo*MM + colo;
        #pragma unroll
        for (int j = 0; j < 4; ++j) {
            const int co = g*4 + j;
            const size_t idx = (size_t)co*NPIX + pix;
            const float rr = acc[grp][0][j], ii = acc[grp][1][j];
            if (MODE == 0) {
                const float2 xc = x[idx];
                out[idx] = make_float2(rr - xc.x, ii - xc.y);
            } else if (MODE == 1) {
                const float2 tc = x[idx];
                const float2 pc = aux[idx];
                const float mv = mask8[idx] ? 1.f : 0.f;
                const float qr = rr - tc.x + (mv + am)*pc.x;
                const float qi = ii - tc.y + (mv + am)*pc.y;
                out[idx] = make_float2(qr, qi);
                part.x += qr*pc.x + qi*pc.y;
                part.y += qi*pc.x - qr*pc.y;
            } else {
                const float2 tc = x[idx];
                const float2 wc = aux[idx];
                const float mv = mask8[idx] ? 1.f : 0.f;
                const float kr_ = ks[(size_t)pix*32 + co];
                const float ki_ = ks[(size_t)pix*32 + co + 16];
                const float zr  = z[(size_t)pix*32 + co];
                const float zi  = z[(size_t)pix*32 + co + 16];
                const float pr = mv*kr_ + am*zr - (rr - tc.x) - (mv + am)*wc.x;
                const float pi = mv*ki_ + am*zi - (ii - tc.y) - (mv + am)*wc.y;
                out[idx]  = make_float2(pr, pi);
                out2[idx] = make_float2(pr, pi);
                part.x += pr*pr + pi*pi;
            }
        }
    }
    if (MODE >= 1) {
        __syncthreads();
        part = block_reduce2(part);
        if (t == 0) partials[bi] = part;
    }
}

__global__ void finalize_rr(const float2* __restrict__ partials, float* __restrict__ scal, int n) {
    float2 s = make_float2(0.f, 0.f);
    for (int i = threadIdx.x; i < n; i += blockDim.x) { s.x += partials[i].x; s.y += partials[i].y; }
    s = block_reduce2(s);
    if (threadIdx.x == 0) scal[0] = s.x;
}

__global__ void finalize_alpha(const float2* __restrict__ partials, float* __restrict__ scal, int n) {
    float2 s = make_float2(0.f, 0.f);
    for (int i = threadIdx.x; i < n; i += blockDim.x) { s.x += partials[i].x; s.y += partials[i].y; }
    s = block_reduce2(s);
    if (threadIdx.x == 0) {
        const float rr = scal[0];
        const float d = s.x*s.x + s.y*s.y;
        scal[1] =  rr * s.x / d;
        scal[2] = -rr * s.y / d;
    }
}

__global__ void update_br(float2* __restrict__ b, const float2* __restrict__ p,
                          float2* __restrict__ r, const float2* __restrict__ q,
                          const float* __restrict__ scal, float2* __restrict__ partials) {
    const float ar = scal[1], ai = scal[2];
    float2 s = make_float2(0.f, 0.f);
    for (int e = blockIdx.x*256 + threadIdx.x; e < N2; e += NRED*256) {
        const float2 pv = p[e], qv = q[e];
        float2 bv = b[e], rv = r[e];
        bv.x += ar*pv.x - ai*pv.y;
        bv.y += ar*pv.y + ai*pv.x;
        rv.x -= ar*qv.x - ai*qv.y;
        rv.y -= ar*qv.y + ai*qv.x;
        b[e] = bv; r[e] = rv;
        s.x += rv.x*rv.x + rv.y*rv.y;
    }
    s = block_reduce2(s);
    if (threadIdx.x == 0) partials[blockIdx.x] = s;
}

__global__ void finalize_beta(const float2* __restrict__ partials, float* __restrict__ scal) {
    float2 v = partials[threadIdx.x];
    v = block_reduce2(v);
    if (threadIdx.x == 0) {
        const float rn = v.x;
        scal[3] = rn / scal[0];
        scal[0] = rn;
    }
}

__global__ void update_p(float2* __restrict__ p, const float2* __restrict__ r,
                         const float* __restrict__ scal) {
    const float beta = scal[3];
    const int e = blockIdx.x*256 + threadIdx.x;
    if (e < N2) {
        const float2 pv = p[e], rv = r[e];
        p[e] = make_float2(rv.x + beta*pv.x, rv.y + beta*pv.y);
    }
}

__global__ void pack_out(const float2* __restrict__ b, float* __restrict__ out) {
    const int e = blockIdx.x*256 + threadIdx.x;
    if (e >= 32*NPIX) return;
    const int pix = e >> 5;
    const int cc  = e & 31;
    const float2 v = b[(size_t)(cc & 15)*NPIX + pix];
    out[e] = (cc < 16) ? v.x : v.y;
}

extern "C" void kernel_launch(void* const* d_in, const int* in_sizes, int n_in,
                              void* d_out, int out_size, void* d_ws, size_t ws_size,
                              hipStream_t stream) {
    const float* z    = (const float*)d_in[0];
    const float* ks   = (const float*)d_in[1];
    const float* kr   = (const float*)d_in[2];
    const float* ki   = (const float*)d_in[3];
    const float* prev = (const float*)d_in[5];
    const float* miu  = (const float*)d_in[6];
    float* out = (float*)d_out;

    char* w = (char*)d_ws;
    const size_t FB = (size_t)N2 * sizeof(float2);
    float2* wsf = (float2*)w; w += FB;    // b (in-place)
    float2* pf  = (float2*)w; w += FB;
    float2* rf  = (float2*)w; w += FB;
    float2* qf  = (float2*)w; w += FB;
    float2* tf  = (float2*)w; w += FB;
    u32* wbuf   = (u32*)w;   w += (size_t)2*162*256*sizeof(u32);   // 331776 B
    uint8_t* mask8 = (uint8_t*)w; w += (size_t)N2;
    w = (char*)(((uintptr_t)w + 255) & ~(uintptr_t)255);
    float2* partials = (float2*)w; w += (size_t)NCBLK * sizeof(float2);
    float*  scal     = (float*)w;

    const u32* wbF = wbuf;
    const u32* wbB = wbuf + (size_t)162*256;

    prep_weights<<<81, 256, 0, stream>>>(kr, ki, wbuf);
    prep_fields<<<576, 256, 0, stream>>>(ks, prev, wsf, mask8);

    conv9<0><<<NCBLK, 512, 0, stream>>>(wsf, wbF, tf, nullptr, nullptr, nullptr, nullptr, nullptr, nullptr, nullptr);
    conv9<2><<<NCBLK, 512, 0, stream>>>(tf, wbB, pf, rf, wsf, ks, z, mask8, miu, partials);
    finalize_rr<<<1, 256, 0, stream>>>(partials, scal, NCBLK);

    for (int it = 0; it < 10; ++it) {
        conv9<0><<<NCBLK, 512, 0, stream>>>(pf, wbF, tf, nullptr, nullptr, nullptr, nullptr, nullptr, nullptr, nullptr);
        conv9<1><<<NCBLK, 512, 0, stream>>>(tf, wbB, qf, nullptr, pf, nullptr, nullptr, mask8, miu, partials);
        finalize_alpha<<<1, 256, 0, stream>>>(partials, scal, NCBLK);
        update_br<<<NRED, 256, 0, stream>>>(wsf, pf, rf, qf, scal, partials);
        finalize_beta<<<1, NRED, 0, stream>>>(partials, scal);
        update_p<<<9216, 256, 0, stream>>>(pf, rf, scal);
    }

    pack_out<<<18432, 256, 0, stream>>>(wsf, out);
}

// Round 9
// 1325.760 us; speedup vs baseline: 1.7797x; 1.2697x over previous
//
#include <hip/hip_runtime.h>
#include <stdint.h>

// SPIRiT CG reconstruction. Convs: single-product bf16 MFMA (W and X both
// RN-rounded bf16), per-tap implicit GEMM M=16 c_out, N=16 pixels,
// K=32 = 16 c_in x {re,im}. Fields planar complex float2 f[c][384*384].
// Conv kernel: 256 threads (4 waves) per 16x16 tile, wave owns 4 output rows.
// Stage-once 24x24 slab (64 B/px, 36.9 KB -> 4 blocks/CU). Loop q-outer /
// p-inner unrolled with X-row register rotation (3/4 frags reused across p)
// + 3-tap W register ring. ORDER: MFQ(current) THEN LW(prefetch) — R8's bug
// was the reverse (prefetch clobbered the ring slot before the MFMA read it).

#define MM 384
#define NPIX (MM*MM)          // 147456
#define N2 (16*NPIX)
#define NRED 512
#define NCBLK 576             // 24 x 24 tiles of 16x16 pixels

typedef __attribute__((ext_vector_type(8))) short short8;
typedef __attribute__((ext_vector_type(4))) float f32x4;
typedef unsigned int u32;

__device__ __forceinline__ float2 block_reduce2(float2 v) {
    #pragma unroll
    for (int off = 32; off > 0; off >>= 1) {
        v.x += __shfl_down(v.x, off);
        v.y += __shfl_down(v.y, off);
    }
    __shared__ float2 tmp[8];
    const int wid = threadIdx.x >> 6, lid = threadIdx.x & 63;
    if (lid == 0) tmp[wid] = v;
    __syncthreads();
    if (threadIdx.x == 0) {
        const int nw = blockDim.x >> 6;
        for (int i = 1; i < nw; ++i) { v.x += tmp[i].x; v.y += tmp[i].y; }
    }
    return v;
}

__device__ __forceinline__ u32 bf16rn(float f) {   // round-to-nearest-even bf16
    const u32 u = __float_as_uint(f);
    return (u + 0x7FFFu + ((u >> 16) & 1u)) >> 16;
}

// Weight fragments (RN bf16): [dir][slot=q*9+p][hf][lane64][4 u32]  (q-major)
// hf=0 rows: [Wr | -Wi] (-> rr), hf=1 rows: [Wi | Wr] (-> ii); lane = co + 16*kgroup.
// Tap block = 2 KB.
__global__ void prep_weights(const float* __restrict__ kr, const float* __restrict__ ki,
                             u32* __restrict__ wbuf) {
    const int e = blockIdx.x * 256 + threadIdx.x;
    if (e >= 20736) return;    // 2 dir x 81 tap x 2 hf x 64 lane
    const int lane = e & 63;
    int r = e >> 6;
    const int hf = r & 1; r >>= 1;
    const int q = r % 9; r /= 9;
    const int p = r % 9; r /= 9;
    const int dir = r;
    const int co = lane & 15, g = lane >> 4;
    float vv[8];
    #pragma unroll
    for (int t = 0; t < 8; ++t) {
        const int kc = 8 * g + t;
        const int ci = kc & 15;
        const int isI = kc >> 4;
        int sidx;
        if (dir == 0) sidx = (q*9 + p)*256 + ci*16 + co;          // Wf[co,ci,p,q]=K[q,p,ci,co]
        else          sidx = ((8-q)*9 + (8-p))*256 + co*16 + ci;  // Wb = conj flip swap
        const float wr = kr[sidx];
        const float wi = (dir == 0) ? ki[sidx] : -ki[sidx];
        vv[t] = (hf == 0) ? (isI ? -wi : wr) : (isI ? wr : wi);
    }
    u32 pk[4];
    #pragma unroll
    for (int t = 0; t < 4; ++t) pk[t] = bf16rn(vv[2*t]) | (bf16rn(vv[2*t+1]) << 16);
    u32* o = wbuf + (size_t)(dir*162 + (q*9 + p)*2 + hf)*256 + lane*4;
    *(uint4*)o = make_uint4(pk[0], pk[1], pk[2], pk[3]);
}

__global__ void prep_fields(const float* __restrict__ ks, const float* __restrict__ prev,
                            float2* __restrict__ wsf, uint8_t* __restrict__ mask8) {
    const int pix = blockIdx.x * blockDim.x + threadIdx.x;
    if (pix >= NPIX) return;
    #pragma unroll
    for (int c = 0; c < 16; ++c) {
        const float krr = ks[(size_t)pix*32 + c];
        const float kii = ks[(size_t)pix*32 + c + 16];
        mask8[(size_t)c*NPIX + pix] = (krr != 0.f || kii != 0.f) ? 1 : 0;
        wsf[(size_t)c*NPIX + pix] = make_float2(prev[(size_t)pix*32 + c], prev[(size_t)pix*32 + c + 16]);
    }
}

// MODE 0: out = conv(x) - x
// MODE 1: out = conv(x) - x + (mask+am)*aux ; partial += out*conj(aux)
// MODE 2: out=out2 = mask*kk + am*z - (conv(x)-x) - (mask+am)*aux ; partial += |out|^2
template<int MODE>
__global__ __launch_bounds__(256, 4)
void conv9(const float2* __restrict__ x, const u32* __restrict__ Wd,
           float2* __restrict__ out, float2* __restrict__ out2,
           const float2* __restrict__ aux, const float* __restrict__ ks,
           const float* __restrict__ z, const uint8_t* __restrict__ mask8,
           const float* __restrict__ miu, float2* __restrict__ partials)
{
    __shared__ __align__(16) char Xs[24*24*64];   // 36864 B
    const int t = threadIdx.x;
    const int bi = blockIdx.x;
    const int i0 = (bi / 24) * 16;
    const int j0 = (bi % 24) * 16;
    const int w = t >> 6, lane = t & 63;
    const int m = lane & 15, g = lane >> 4;

    // ---- stage 24x24 slab, bf16 RN, 64 B/px: 4 slots of 16B,
    //      content c (0:re ci0-7, 1:re ci8-15, 2:im ci0-7, 3:im ci8-15)
    //      stored at slot c ^ (col&3).
    for (int u = t; u < 24*24; u += 256) {
        const int col = u % 24, row = u / 24;
        const int row_g = i0 - 4 + row, col_g = j0 - 4 + col;
        const bool valid = ((unsigned)row_g < MM) && ((unsigned)col_g < MM);
        const float2* src = x + (size_t)row_g*MM + col_g;
        float2 v[16];
        #pragma unroll
        for (int ci = 0; ci < 16; ++ci)
            v[ci] = valid ? src[(size_t)ci*NPIX] : make_float2(0.f, 0.f);
        u32 c0[4], c1[4], c2[4], c3[4];
        #pragma unroll
        for (int j = 0; j < 4; ++j) {
            c0[j] = bf16rn(v[2*j].x)     | (bf16rn(v[2*j+1].x) << 16);
            c1[j] = bf16rn(v[8+2*j].x)   | (bf16rn(v[9+2*j].x) << 16);
            c2[j] = bf16rn(v[2*j].y)     | (bf16rn(v[2*j+1].y) << 16);
            c3[j] = bf16rn(v[8+2*j].y)   | (bf16rn(v[9+2*j].y) << 16);
        }
        const int k3 = col & 3;
        char* pb = Xs + (size_t)(row*24 + col)*64;
        *(uint4*)(pb + (((0 ^ k3)) << 4)) = make_uint4(c0[0], c0[1], c0[2], c0[3]);
        *(uint4*)(pb + (((1 ^ k3)) << 4)) = make_uint4(c1[0], c1[1], c1[2], c1[3]);
        *(uint4*)(pb + (((2 ^ k3)) << 4)) = make_uint4(c2[0], c2[1], c2[2], c2[3]);
        *(uint4*)(pb + (((3 ^ k3)) << 4)) = make_uint4(c3[0], c3[1], c3[2], c3[3]);
    }
    __syncthreads();

    f32x4 acc[4][2];
    #pragma unroll
    for (int a = 0; a < 4; ++a)
        #pragma unroll
        for (int h = 0; h < 2; ++h) acc[a][h] = (f32x4){0.f, 0.f, 0.f, 0.f};

    // ---- 81 taps, q-outer / p-inner (unrolled 9). Wave owns output rows
    //      4w..4w+3; tap p uses slab rows 4w+p..4w+p+3 -> rotate X0..X4.
    //      W ring WA/WB/WC: tap (q,p) uses slot p%3; COMPUTE THEN PREFETCH.
    const char* wl = (const char*)Wd + (lane << 4);
    short8 WA[2], WB[2], WC[2];

    #define LW(WS, ADDR) do { \
        WS[0] = *(const short8*)(ADDR); \
        WS[1] = *(const short8*)((ADDR) + 1024); } while (0)

    #define MFQ(Xa, Xb, Xc, Xd, WS) do { \
        acc[0][0] = __builtin_amdgcn_mfma_f32_16x16x32_bf16(WS[0], Xa, acc[0][0], 0, 0, 0); \
        acc[1][0] = __builtin_amdgcn_mfma_f32_16x16x32_bf16(WS[0], Xb, acc[1][0], 0, 0, 0); \
        acc[2][0] = __builtin_amdgcn_mfma_f32_16x16x32_bf16(WS[0], Xc, acc[2][0], 0, 0, 0); \
        acc[3][0] = __builtin_amdgcn_mfma_f32_16x16x32_bf16(WS[0], Xd, acc[3][0], 0, 0, 0); \
        acc[0][1] = __builtin_amdgcn_mfma_f32_16x16x32_bf16(WS[1], Xa, acc[0][1], 0, 0, 0); \
        acc[1][1] = __builtin_amdgcn_mfma_f32_16x16x32_bf16(WS[1], Xb, acc[1][1], 0, 0, 0); \
        acc[2][1] = __builtin_amdgcn_mfma_f32_16x16x32_bf16(WS[1], Xc, acc[2][1], 0, 0, 0); \
        acc[3][1] = __builtin_amdgcn_mfma_f32_16x16x32_bf16(WS[1], Xd, acc[3][1], 0, 0, 0); } while (0)

    LW(WA, wl);            // (q0,p0)
    LW(WB, wl + 2048);     // (q0,p1)
    LW(WC, wl + 4096);     // (q0,p2)

    #pragma unroll 1
    for (int qq = 0; qq < 9; ++qq) {
        const char* wq = wl + (size_t)qq * 18432;
        const int colq = m + qq;
        const char* xb = Xs + (size_t)((4*w)*24 + colq)*64 + ((g ^ (colq & 3)) << 4);
        short8 X0 = *(const short8*)(xb);
        short8 X1 = *(const short8*)(xb + 1536);
        short8 X2 = *(const short8*)(xb + 2*1536);
        short8 X3 = *(const short8*)(xb + 3*1536);
        short8 X4;
        // compute tap (qq,p) with ring slot p%3, THEN prefetch tap (qq,p+3)
        X4 = *(const short8*)(xb + 4*1536);  MFQ(X0, X1, X2, X3, WA); LW(WA, wq + 3*2048);   // p0
        X0 = *(const short8*)(xb + 5*1536);  MFQ(X1, X2, X3, X4, WB); LW(WB, wq + 4*2048);   // p1
        X1 = *(const short8*)(xb + 6*1536);  MFQ(X2, X3, X4, X0, WC); LW(WC, wq + 5*2048);   // p2
        X2 = *(const short8*)(xb + 7*1536);  MFQ(X3, X4, X0, X1, WA); LW(WA, wq + 6*2048);   // p3
        X3 = *(const short8*)(xb + 8*1536);  MFQ(X4, X0, X1, X2, WB); LW(WB, wq + 7*2048);   // p4
        X4 = *(const short8*)(xb + 9*1536);  MFQ(X0, X1, X2, X3, WC); LW(WC, wq + 8*2048);   // p5
        X0 = *(const short8*)(xb + 10*1536); MFQ(X1, X2, X3, X4, WA); LW(WA, wq + 9*2048);   // p6 ; pf (q+1,p0)
        X1 = *(const short8*)(xb + 11*1536); MFQ(X2, X3, X4, X0, WB); LW(WB, wq + 10*2048);  // p7 ; pf (q+1,p1)
                                             MFQ(X3, X4, X0, X1, WC); LW(WC, wq + 11*2048); // p8 ; pf (q+1,p2)
    }
    #undef LW
    #undef MFQ
    // (last column's prefetches over-read a few KB past this dir's W region;
    //  values unused, addresses stay inside d_ws — harmless.)

    // ---- epilogue: C/D col = lane&15 = pixel col, row = g*4+j = co
    const float am = (MODE >= 1) ? fabsf(miu[0]) : 0.f;
    float2 part = make_float2(0.f, 0.f);
    #pragma unroll
    for (int r = 0; r < 4; ++r) {
        const int rowo = i0 + 4*w + r;
        const int colo = j0 + m;
        const int pix = rowo*MM + colo;
        #pragma unroll
        for (int j = 0; j < 4; ++j) {
            const int co = g*4 + j;
            const size_t idx = (size_t)co*NPIX + pix;
            const float rr = acc[r][0][j], ii = acc[r][1][j];
            if (MODE == 0) {
                const float2 xc = x[idx];
                out[idx] = make_float2(rr - xc.x, ii - xc.y);
            } else if (MODE == 1) {
                const float2 tc = x[idx];
                const float2 pc = aux[idx];
                const float mv = mask8[idx] ? 1.f : 0.f;
                const float qr = rr - tc.x + (mv + am)*pc.x;
                const float qi = ii - tc.y + (mv + am)*pc.y;
                out[idx] = make_float2(qr, qi);
                part.x += qr*pc.x + qi*pc.y;
                part.y += qi*pc.x - qr*pc.y;
            } else {
                const float2 tc = x[idx];
                const float2 wc = aux[idx];
                const float mv = mask8[idx] ? 1.f : 0.f;
                const float kr_ = ks[(size_t)pix*32 + co];
                const float ki_ = ks[(size_t)pix*32 + co + 16];
                const float zr  = z[(size_t)pix*32 + co];
                const float zi  = z[(size_t)pix*32 + co + 16];
                const float pr = mv*kr_ + am*zr - (rr - tc.x) - (mv + am)*wc.x;
                const float pi = mv*ki_ + am*zi - (ii - tc.y) - (mv + am)*wc.y;
                out[idx]  = make_float2(pr, pi);
                out2[idx] = make_float2(pr, pi);
                part.x += pr*pr + pi*pi;
            }
        }
    }
    if (MODE >= 1) {
        __syncthreads();
        part = block_reduce2(part);
        if (t == 0) partials[bi] = part;
    }
}

__global__ void finalize_rr(const float2* __restrict__ partials, float* __restrict__ scal, int n) {
    float2 s = make_float2(0.f, 0.f);
    for (int i = threadIdx.x; i < n; i += blockDim.x) { s.x += partials[i].x; s.y += partials[i].y; }
    s = block_reduce2(s);
    if (threadIdx.x == 0) scal[0] = s.x;
}

__global__ void finalize_alpha(const float2* __restrict__ partials, float* __restrict__ scal, int n) {
    float2 s = make_float2(0.f, 0.f);
    for (int i = threadIdx.x; i < n; i += blockDim.x) { s.x += partials[i].x; s.y += partials[i].y; }
    s = block_reduce2(s);
    if (threadIdx.x == 0) {
        const float rr = scal[0];
        const float d = s.x*s.x + s.y*s.y;
        scal[1] =  rr * s.x / d;
        scal[2] = -rr * s.y / d;
    }
}

__global__ void update_br(float2* __restrict__ b, const float2* __restrict__ p,
                          float2* __restrict__ r, const float2* __restrict__ q,
                          const float* __restrict__ scal, float2* __restrict__ partials) {
    const float ar = scal[1], ai = scal[2];
    float2 s = make_float2(0.f, 0.f);
    for (int e = blockIdx.x*256 + threadIdx.x; e < N2; e += NRED*256) {
        const float2 pv = p[e], qv = q[e];
        float2 bv = b[e], rv = r[e];
        bv.x += ar*pv.x - ai*pv.y;
        bv.y += ar*pv.y + ai*pv.x;
        rv.x -= ar*qv.x - ai*qv.y;
        rv.y -= ar*qv.y + ai*qv.x;
        b[e] = bv; r[e] = rv;
        s.x += rv.x*rv.x + rv.y*rv.y;
    }
    s = block_reduce2(s);
    if (threadIdx.x == 0) partials[blockIdx.x] = s;
}

__global__ void finalize_beta(const float2* __restrict__ partials, float* __restrict__ scal) {
    float2 v = partials[threadIdx.x];
    v = block_reduce2(v);
    if (threadIdx.x == 0) {
        const float rn = v.x;
        scal[3] = rn / scal[0];
        scal[0] = rn;
    }
}

__global__ void update_p(float2* __restrict__ p, const float2* __restrict__ r,
                         const float* __restrict__ scal) {
    const float beta = scal[3];
    const int e = blockIdx.x*256 + threadIdx.x;
    if (e < N2) {
        const float2 pv = p[e], rv = r[e];
        p[e] = make_float2(rv.x + beta*pv.x, rv.y + beta*pv.y);
    }
}

__global__ void pack_out(const float2* __restrict__ b, float* __restrict__ out) {
    const int e = blockIdx.x*256 + threadIdx.x;
    if (e >= 32*NPIX) return;
    const int pix = e >> 5;
    const int cc  = e & 31;
    const float2 v = b[(size_t)(cc & 15)*NPIX + pix];
    out[e] = (cc < 16) ? v.x : v.y;
}

extern "C" void kernel_launch(void* const* d_in, const int* in_sizes, int n_in,
                              void* d_out, int out_size, void* d_ws, size_t ws_size,
                              hipStream_t stream) {
    const float* z    = (const float*)d_in[0];
    const float* ks   = (const float*)d_in[1];
    const float* kr   = (const float*)d_in[2];
    const float* ki   = (const float*)d_in[3];
    const float* prev = (const float*)d_in[5];
    const float* miu  = (const float*)d_in[6];
    float* out = (float*)d_out;

    char* w = (char*)d_ws;
    const size_t FB = (size_t)N2 * sizeof(float2);
    float2* wsf = (float2*)w; w += FB;    // b (in-place)
    float2* pf  = (float2*)w; w += FB;
    float2* rf  = (float2*)w; w += FB;
    float2* qf  = (float2*)w; w += FB;
    float2* tf  = (float2*)w; w += FB;
    u32* wbuf   = (u32*)w;   w += (size_t)2*162*256*sizeof(u32);   // 331776 B
    uint8_t* mask8 = (uint8_t*)w; w += (size_t)N2;
    w = (char*)(((uintptr_t)w + 255) & ~(uintptr_t)255);
    float2* partials = (float2*)w; w += (size_t)NCBLK * sizeof(float2);
    float*  scal     = (float*)w;

    const u32* wbF = wbuf;
    const u32* wbB = wbuf + (size_t)162*256;

    prep_weights<<<81, 256, 0, stream>>>(kr, ki, wbuf);
    prep_fields<<<576, 256, 0, stream>>>(ks, prev, wsf, mask8);

    conv9<0><<<NCBLK, 256, 0, stream>>>(wsf, wbF, tf, nullptr, nullptr, nullptr, nullptr, nullptr, nullptr, nullptr);
    conv9<2><<<NCBLK, 256, 0, stream>>>(tf, wbB, pf, rf, wsf, ks, z, mask8, miu, partials);
    finalize_rr<<<1, 256, 0, stream>>>(partials, scal, NCBLK);

    for (int it = 0; it < 10; ++it) {
        conv9<0><<<NCBLK, 256, 0, stream>>>(pf, wbF, tf, nullptr, nullptr, nullptr, nullptr, nullptr, nullptr, nullptr);
        conv9<1><<<NCBLK, 256, 0, stream>>>(tf, wbB, qf, nullptr, pf, nullptr, nullptr, mask8, miu, partials);
        finalize_alpha<<<1, 256, 0, stream>>>(partials, scal, NCBLK);
        update_br<<<NRED, 256, 0, stream>>>(wsf, pf, rf, qf, scal, partials);
        finalize_beta<<<1, NRED, 0, stream>>>(partials, scal);
        update_p<<<9216, 256, 0, stream>>>(pf, rf, scal);
    }

    pack_out<<<18432, 256, 0, stream>>>(wsf, out);
}

// Round 10
// 1232.282 us; speedup vs baseline: 1.9147x; 1.0759x over previous
//
#include <hip/hip_runtime.h>
#include <stdint.h>

// SPIRiT CG reconstruction. Convs: single-product bf16 MFMA (W and X RN bf16),
// per-tap implicit GEMM M=16 c_out, N=16 pixels, K=32 = 16 c_in x {re,im}.
// Conv kernel: 512 threads (8 waves) per 16x16 tile. Complex product split
// across wave pairs: wave w(0..3) = REAL acc (hf0 frags [Wr|-Wi]) for rows
// 4w..4w+3; wave w+4 = IMAG acc (hf1 frags [Wi|Wr]) same rows. Each wave
// loads 1 W frag/tap (halves the duplicated W stream vs 2-frag waves) and
// 4 MFMAs/tap. Stage-once 24x24 bf16 slab (36.9 KB). q-outer/p-inner with
// X register rotation (5-reg ring) + 3-tap W register ring, compute-then-
// prefetch ordering (R8 bug: reversed order clobbered the ring).

#define MM 384
#define NPIX (MM*MM)          // 147456
#define N2 (16*NPIX)
#define NRED 512
#define NCBLK 576             // 24 x 24 tiles of 16x16 pixels

typedef __attribute__((ext_vector_type(8))) short short8;
typedef __attribute__((ext_vector_type(4))) float f32x4;
typedef unsigned int u32;

__device__ __forceinline__ float2 block_reduce2(float2 v) {
    #pragma unroll
    for (int off = 32; off > 0; off >>= 1) {
        v.x += __shfl_down(v.x, off);
        v.y += __shfl_down(v.y, off);
    }
    __shared__ float2 tmp[8];
    const int wid = threadIdx.x >> 6, lid = threadIdx.x & 63;
    if (lid == 0) tmp[wid] = v;
    __syncthreads();
    if (threadIdx.x == 0) {
        const int nw = blockDim.x >> 6;
        for (int i = 1; i < nw; ++i) { v.x += tmp[i].x; v.y += tmp[i].y; }
    }
    return v;
}

__device__ __forceinline__ u32 bf16rn(float f) {   // round-to-nearest-even bf16
    const u32 u = __float_as_uint(f);
    return (u + 0x7FFFu + ((u >> 16) & 1u)) >> 16;
}

// Weight fragments (RN bf16): [dir][slot=q*9+p][hf][lane64][4 u32]  (q-major)
// hf=0 rows: [Wr | -Wi] (-> real), hf=1 rows: [Wi | Wr] (-> imag);
// lane = co + 16*kgroup. Tap block = 2 KB (1 KB per hf).
__global__ void prep_weights(const float* __restrict__ kr, const float* __restrict__ ki,
                             u32* __restrict__ wbuf) {
    const int e = blockIdx.x * 256 + threadIdx.x;
    if (e >= 20736) return;    // 2 dir x 81 tap x 2 hf x 64 lane
    const int lane = e & 63;
    int r = e >> 6;
    const int hf = r & 1; r >>= 1;
    const int q = r % 9; r /= 9;
    const int p = r % 9; r /= 9;
    const int dir = r;
    const int co = lane & 15, g = lane >> 4;
    float vv[8];
    #pragma unroll
    for (int t = 0; t < 8; ++t) {
        const int kc = 8 * g + t;
        const int ci = kc & 15;
        const int isI = kc >> 4;
        int sidx;
        if (dir == 0) sidx = (q*9 + p)*256 + ci*16 + co;          // Wf[co,ci,p,q]=K[q,p,ci,co]
        else          sidx = ((8-q)*9 + (8-p))*256 + co*16 + ci;  // Wb = conj flip swap
        const float wr = kr[sidx];
        const float wi = (dir == 0) ? ki[sidx] : -ki[sidx];
        vv[t] = (hf == 0) ? (isI ? -wi : wr) : (isI ? wr : wi);
    }
    u32 pk[4];
    #pragma unroll
    for (int t = 0; t < 4; ++t) pk[t] = bf16rn(vv[2*t]) | (bf16rn(vv[2*t+1]) << 16);
    u32* o = wbuf + (size_t)(dir*162 + (q*9 + p)*2 + hf)*256 + lane*4;
    *(uint4*)o = make_uint4(pk[0], pk[1], pk[2], pk[3]);
}

__global__ void prep_fields(const float* __restrict__ ks, const float* __restrict__ prev,
                            float2* __restrict__ wsf, uint8_t* __restrict__ mask8) {
    const int pix = blockIdx.x * blockDim.x + threadIdx.x;
    if (pix >= NPIX) return;
    #pragma unroll
    for (int c = 0; c < 16; ++c) {
        const float krr = ks[(size_t)pix*32 + c];
        const float kii = ks[(size_t)pix*32 + c + 16];
        mask8[(size_t)c*NPIX + pix] = (krr != 0.f || kii != 0.f) ? 1 : 0;
        wsf[(size_t)c*NPIX + pix] = make_float2(prev[(size_t)pix*32 + c], prev[(size_t)pix*32 + c + 16]);
    }
}

// MODE 0: out = conv(x) - x
// MODE 1: out = conv(x) - x + (mask+am)*aux ; partial += out*conj(aux)
// MODE 2: out=out2 = mask*kk + am*z - (conv(x)-x) - (mask+am)*aux ; partial += |out|^2
// Each wave handles ONE component (hf): all epilogue math is separable.
template<int MODE>
__global__ __launch_bounds__(512, 4)
void conv9(const float2* __restrict__ x, const u32* __restrict__ Wd,
           float2* __restrict__ out, float2* __restrict__ out2,
           const float2* __restrict__ aux, const float* __restrict__ ks,
           const float* __restrict__ z, const uint8_t* __restrict__ mask8,
           const float* __restrict__ miu, float2* __restrict__ partials)
{
    __shared__ __align__(16) char Xs[24*24*64];   // 36864 B
    const int t = threadIdx.x;
    const int bi = blockIdx.x;
    const int i0 = (bi / 24) * 16;
    const int j0 = (bi % 24) * 16;
    const int w = t >> 6, lane = t & 63;
    const int hf = w >> 2;          // 0: real component, 1: imag component
    const int wr = w & 3;           // row group (rows 4wr..4wr+3)
    const int m = lane & 15, g = lane >> 4;

    // ---- stage 24x24 slab, bf16 RN, 64 B/px: 4 slots of 16B,
    //      content c (0:re ci0-7, 1:re ci8-15, 2:im ci0-7, 3:im ci8-15)
    //      stored at slot c ^ (col&3).
    for (int u = t; u < 24*24; u += 512) {
        const int col = u % 24, row = u / 24;
        const int row_g = i0 - 4 + row, col_g = j0 - 4 + col;
        const bool valid = ((unsigned)row_g < MM) && ((unsigned)col_g < MM);
        const float2* src = x + (size_t)row_g*MM + col_g;
        float2 v[16];
        #pragma unroll
        for (int ci = 0; ci < 16; ++ci)
            v[ci] = valid ? src[(size_t)ci*NPIX] : make_float2(0.f, 0.f);
        u32 c0[4], c1[4], c2[4], c3[4];
        #pragma unroll
        for (int j = 0; j < 4; ++j) {
            c0[j] = bf16rn(v[2*j].x)     | (bf16rn(v[2*j+1].x) << 16);
            c1[j] = bf16rn(v[8+2*j].x)   | (bf16rn(v[9+2*j].x) << 16);
            c2[j] = bf16rn(v[2*j].y)     | (bf16rn(v[2*j+1].y) << 16);
            c3[j] = bf16rn(v[8+2*j].y)   | (bf16rn(v[9+2*j].y) << 16);
        }
        const int k3 = col & 3;
        char* pb = Xs + (size_t)(row*24 + col)*64;
        *(uint4*)(pb + (((0 ^ k3)) << 4)) = make_uint4(c0[0], c0[1], c0[2], c0[3]);
        *(uint4*)(pb + (((1 ^ k3)) << 4)) = make_uint4(c1[0], c1[1], c1[2], c1[3]);
        *(uint4*)(pb + (((2 ^ k3)) << 4)) = make_uint4(c2[0], c2[1], c2[2], c2[3]);
        *(uint4*)(pb + (((3 ^ k3)) << 4)) = make_uint4(c3[0], c3[1], c3[2], c3[3]);
    }
    __syncthreads();

    f32x4 acc[4];
    #pragma unroll
    for (int a = 0; a < 4; ++a) acc[a] = (f32x4){0.f, 0.f, 0.f, 0.f};

    // ---- 81 taps, q-outer / p-inner (unrolled 9). Wave owns output rows
    //      4wr..4wr+3, component hf; tap p uses slab rows 4wr+p..4wr+p+3 ->
    //      rotate X0..X4. W ring WA/WB/WC (1 frag each, this wave's hf);
    //      tap (q,p) uses slot p%3; COMPUTE THEN PREFETCH.
    const char* wl = (const char*)Wd + (lane << 4) + (hf << 10);
    short8 WA, WB, WC;

    #define LW(WS, ADDR) do { WS = *(const short8*)(ADDR); } while (0)

    #define MFQ(Xa, Xb, Xc, Xd, WS) do { \
        acc[0] = __builtin_amdgcn_mfma_f32_16x16x32_bf16(WS, Xa, acc[0], 0, 0, 0); \
        acc[1] = __builtin_amdgcn_mfma_f32_16x16x32_bf16(WS, Xb, acc[1], 0, 0, 0); \
        acc[2] = __builtin_amdgcn_mfma_f32_16x16x32_bf16(WS, Xc, acc[2], 0, 0, 0); \
        acc[3] = __builtin_amdgcn_mfma_f32_16x16x32_bf16(WS, Xd, acc[3], 0, 0, 0); } while (0)

    LW(WA, wl);            // (q0,p0)
    LW(WB, wl + 2048);     // (q0,p1)
    LW(WC, wl + 4096);     // (q0,p2)

    #pragma unroll 1
    for (int qq = 0; qq < 9; ++qq) {
        const char* wq = wl + (size_t)qq * 18432;
        const int colq = m + qq;
        const char* xb = Xs + (size_t)((4*wr)*24 + colq)*64 + ((g ^ (colq & 3)) << 4);
        short8 X0 = *(const short8*)(xb);
        short8 X1 = *(const short8*)(xb + 1536);
        short8 X2 = *(const short8*)(xb + 2*1536);
        short8 X3 = *(const short8*)(xb + 3*1536);
        short8 X4;
        // compute tap (qq,p) with ring slot p%3, THEN prefetch tap (qq,p+3)
        X4 = *(const short8*)(xb + 4*1536);  MFQ(X0, X1, X2, X3, WA); LW(WA, wq + 3*2048);   // p0
        X0 = *(const short8*)(xb + 5*1536);  MFQ(X1, X2, X3, X4, WB); LW(WB, wq + 4*2048);   // p1
        X1 = *(const short8*)(xb + 6*1536);  MFQ(X2, X3, X4, X0, WC); LW(WC, wq + 5*2048);   // p2
        X2 = *(const short8*)(xb + 7*1536);  MFQ(X3, X4, X0, X1, WA); LW(WA, wq + 6*2048);   // p3
        X3 = *(const short8*)(xb + 8*1536);  MFQ(X4, X0, X1, X2, WB); LW(WB, wq + 7*2048);   // p4
        X4 = *(const short8*)(xb + 9*1536);  MFQ(X0, X1, X2, X3, WC); LW(WC, wq + 8*2048);   // p5
        X0 = *(const short8*)(xb + 10*1536); MFQ(X1, X2, X3, X4, WA); LW(WA, wq + 9*2048);   // p6 ; pf (q+1,p0)
        X1 = *(const short8*)(xb + 11*1536); MFQ(X2, X3, X4, X0, WB); LW(WB, wq + 10*2048);  // p7 ; pf (q+1,p1)
                                             MFQ(X3, X4, X0, X1, WC); LW(WC, wq + 11*2048); // p8 ; pf (q+1,p2)
    }
    #undef LW
    #undef MFQ
    // (last column's prefetches over-read a few KB past this dir's W region;
    //  values unused, addresses stay inside d_ws — harmless.)

    // ---- epilogue: C/D col = lane&15 = pixel col, row = g*4+j = co.
    //      This wave stores only component hf of each float2; cross-component
    //      dot terms are separable and summed in the block reduction.
    const float am = (MODE >= 1) ? fabsf(miu[0]) : 0.f;
    float2 part = make_float2(0.f, 0.f);
    const float* xf  = (const float*)x;
    const float* axf = (const float*)aux;
    float* of  = (float*)out;
    float* o2f = (float*)out2;
    #pragma unroll
    for (int r = 0; r < 4; ++r) {
        const int rowo = i0 + 4*wr + r;
        const int colo = j0 + m;
        const int pix = rowo*MM + colo;
        #pragma unroll
        for (int j = 0; j < 4; ++j) {
            const int co = g*4 + j;
            const size_t idx = (size_t)co*NPIX + pix;
            const float v = acc[r][j];
            if (MODE == 0) {
                of[2*idx + hf] = v - xf[2*idx + hf];
            } else if (MODE == 1) {
                const float tc = xf[2*idx + hf];
                const float2 pc = aux[idx];
                const float pc_c = hf ? pc.y : pc.x;
                const float mv = mask8[idx] ? 1.f : 0.f;
                const float qc = v - tc + (mv + am)*pc_c;
                of[2*idx + hf] = qc;
                // part = sum q*conj(p): re += qr*pr + qi*pi ; im += qi*pr - qr*pi
                part.x += qc * pc_c;
                part.y += hf ? qc * pc.x : -qc * pc.y;
            } else {
                const float tc = xf[2*idx + hf];
                const float wc = axf[2*idx + hf];
                const float mv = mask8[idx] ? 1.f : 0.f;
                const float kc = ks[(size_t)pix*32 + co + 16*hf];
                const float zc = z[(size_t)pix*32 + co + 16*hf];
                const float pc = mv*kc + am*zc - (v - tc) - (mv + am)*wc;
                of[2*idx + hf]  = pc;
                o2f[2*idx + hf] = pc;
                part.x += pc * pc;
            }
        }
    }
    if (MODE >= 1) {
        __syncthreads();
        part = block_reduce2(part);
        if (t == 0) partials[bi] = part;
    }
}

__global__ void finalize_rr(const float2* __restrict__ partials, float* __restrict__ scal, int n) {
    float2 s = make_float2(0.f, 0.f);
    for (int i = threadIdx.x; i < n; i += blockDim.x) { s.x += partials[i].x; s.y += partials[i].y; }
    s = block_reduce2(s);
    if (threadIdx.x == 0) scal[0] = s.x;
}

__global__ void finalize_alpha(const float2* __restrict__ partials, float* __restrict__ scal, int n) {
    float2 s = make_float2(0.f, 0.f);
    for (int i = threadIdx.x; i < n; i += blockDim.x) { s.x += partials[i].x; s.y += partials[i].y; }
    s = block_reduce2(s);
    if (threadIdx.x == 0) {
        const float rr = scal[0];
        const float d = s.x*s.x + s.y*s.y;
        scal[1] =  rr * s.x / d;
        scal[2] = -rr * s.y / d;
    }
}

__global__ void update_br(float2* __restrict__ b, const float2* __restrict__ p,
                          float2* __restrict__ r, const float2* __restrict__ q,
                          const float* __restrict__ scal, float2* __restrict__ partials) {
    const float ar = scal[1], ai = scal[2];
    float2 s = make_float2(0.f, 0.f);
    for (int e = blockIdx.x*256 + threadIdx.x; e < N2; e += NRED*256) {
        const float2 pv = p[e], qv = q[e];
        float2 bv = b[e], rv = r[e];
        bv.x += ar*pv.x - ai*pv.y;
        bv.y += ar*pv.y + ai*pv.x;
        rv.x -= ar*qv.x - ai*qv.y;
        rv.y -= ar*qv.y + ai*qv.x;
        b[e] = bv; r[e] = rv;
        s.x += rv.x*rv.x + rv.y*rv.y;
    }
    s = block_reduce2(s);
    if (threadIdx.x == 0) partials[blockIdx.x] = s;
}

__global__ void finalize_beta(const float2* __restrict__ partials, float* __restrict__ scal) {
    float2 v = partials[threadIdx.x];
    v = block_reduce2(v);
    if (threadIdx.x == 0) {
        const float rn = v.x;
        scal[3] = rn / scal[0];
        scal[0] = rn;
    }
}

__global__ void update_p(float2* __restrict__ p, const float2* __restrict__ r,
                         const float* __restrict__ scal) {
    const float beta = scal[3];
    const int e = blockIdx.x*256 + threadIdx.x;
    if (e < N2) {
        const float2 pv = p[e], rv = r[e];
        p[e] = make_float2(rv.x + beta*pv.x, rv.y + beta*pv.y);
    }
}

__global__ void pack_out(const float2* __restrict__ b, float* __restrict__ out) {
    const int e = blockIdx.x*256 + threadIdx.x;
    if (e >= 32*NPIX) return;
    const int pix = e >> 5;
    const int cc  = e & 31;
    const float2 v = b[(size_t)(cc & 15)*NPIX + pix];
    out[e] = (cc < 16) ? v.x : v.y;
}

extern "C" void kernel_launch(void* const* d_in, const int* in_sizes, int n_in,
                              void* d_out, int out_size, void* d_ws, size_t ws_size,
                              hipStream_t stream) {
    const float* z    = (const float*)d_in[0];
    const float* ks   = (const float*)d_in[1];
    const float* kr   = (const float*)d_in[2];
    const float* ki   = (const float*)d_in[3];
    const float* prev = (const float*)d_in[5];
    const float* miu  = (const float*)d_in[6];
    float* out = (float*)d_out;

    char* w = (char*)d_ws;
    const size_t FB = (size_t)N2 * sizeof(float2);
    float2* wsf = (float2*)w; w += FB;    // b (in-place)
    float2* pf  = (float2*)w; w += FB;
    float2* rf  = (float2*)w; w += FB;
    float2* qf  = (float2*)w; w += FB;
    float2* tf  = (float2*)w; w += FB;
    u32* wbuf   = (u32*)w;   w += (size_t)2*162*256*sizeof(u32);   // 331776 B
    uint8_t* mask8 = (uint8_t*)w; w += (size_t)N2;
    w = (char*)(((uintptr_t)w + 255) & ~(uintptr_t)255);
    float2* partials = (float2*)w; w += (size_t)NCBLK * sizeof(float2);
    float*  scal     = (float*)w;

    const u32* wbF = wbuf;
    const u32* wbB = wbuf + (size_t)162*256;

    prep_weights<<<81, 256, 0, stream>>>(kr, ki, wbuf);
    prep_fields<<<576, 256, 0, stream>>>(ks, prev, wsf, mask8);

    conv9<0><<<NCBLK, 512, 0, stream>>>(wsf, wbF, tf, nullptr, nullptr, nullptr, nullptr, nullptr, nullptr, nullptr);
    conv9<2><<<NCBLK, 512, 0, stream>>>(tf, wbB, pf, rf, wsf, ks, z, mask8, miu, partials);
    finalize_rr<<<1, 256, 0, stream>>>(partials, scal, NCBLK);

    for (int it = 0; it < 10; ++it) {
        conv9<0><<<NCBLK, 512, 0, stream>>>(pf, wbF, tf, nullptr, nullptr, nullptr, nullptr, nullptr, nullptr, nullptr);
        conv9<1><<<NCBLK, 512, 0, stream>>>(tf, wbB, qf, nullptr, pf, nullptr, nullptr, mask8, miu, partials);
        finalize_alpha<<<1, 256, 0, stream>>>(partials, scal, NCBLK);
        update_br<<<NRED, 256, 0, stream>>>(wsf, pf, rf, qf, scal, partials);
        finalize_beta<<<1, NRED, 0, stream>>>(partials, scal);
        update_p<<<9216, 256, 0, stream>>>(pf, rf, scal);
    }

    pack_out<<<18432, 256, 0, stream>>>(wsf, out);
}

// Round 11
// 1142.897 us; speedup vs baseline: 2.0644x; 1.0782x over previous
//
#include <hip/hip_runtime.h>
#include <stdint.h>

// SPIRiT CG reconstruction. Convs: single-product bf16 MFMA (W and X RN bf16),
// per-tap implicit GEMM M=16 c_out, N=16 pixels, K=32 = 16 c_in x {re,im}.
// Conv kernel: 12x16 output tile, 384 threads (6 waves = 2 components x 3
// row-groups). Grid 768 = exactly 3 blocks/CU (perfect balance; R10's 576
// blocks left 64 CUs with 50% more work). Complex product split across wave
// pairs (hf0: [Wr|-Wi] real acc, hf1: [Wi|Wr] imag acc), 1 W frag + 4 MFMAs
// per tap per wave. Stage-once 20x24 bf16 slab (30.7 KB). q-outer/p-inner,
// X register rotation + 3-tap W ring, compute-then-prefetch ordering.

#define MM 384
#define NPIX (MM*MM)          // 147456
#define N2 (16*NPIX)
#define NRED 512
#define NCBLK 768             // 32 row-tiles (12 rows) x 24 col-tiles (16 cols)

typedef __attribute__((ext_vector_type(8))) short short8;
typedef __attribute__((ext_vector_type(4))) float f32x4;
typedef unsigned int u32;

__device__ __forceinline__ float2 block_reduce2(float2 v) {
    #pragma unroll
    for (int off = 32; off > 0; off >>= 1) {
        v.x += __shfl_down(v.x, off);
        v.y += __shfl_down(v.y, off);
    }
    __shared__ float2 tmp[8];
    const int wid = threadIdx.x >> 6, lid = threadIdx.x & 63;
    if (lid == 0) tmp[wid] = v;
    __syncthreads();
    if (threadIdx.x == 0) {
        const int nw = blockDim.x >> 6;
        for (int i = 1; i < nw; ++i) { v.x += tmp[i].x; v.y += tmp[i].y; }
    }
    return v;
}

__device__ __forceinline__ u32 bf16rn(float f) {   // round-to-nearest-even bf16
    const u32 u = __float_as_uint(f);
    return (u + 0x7FFFu + ((u >> 16) & 1u)) >> 16;
}

// Weight fragments (RN bf16): [dir][slot=q*9+p][hf][lane64][4 u32]  (q-major)
// hf=0 rows: [Wr | -Wi] (-> real), hf=1 rows: [Wi | Wr] (-> imag);
// lane = co + 16*kgroup. Tap block = 2 KB (1 KB per hf).
__global__ void prep_weights(const float* __restrict__ kr, const float* __restrict__ ki,
                             u32* __restrict__ wbuf) {
    const int e = blockIdx.x * 256 + threadIdx.x;
    if (e >= 20736) return;    // 2 dir x 81 tap x 2 hf x 64 lane
    const int lane = e & 63;
    int r = e >> 6;
    const int hf = r & 1; r >>= 1;
    const int q = r % 9; r /= 9;
    const int p = r % 9; r /= 9;
    const int dir = r;
    const int co = lane & 15, g = lane >> 4;
    float vv[8];
    #pragma unroll
    for (int t = 0; t < 8; ++t) {
        const int kc = 8 * g + t;
        const int ci = kc & 15;
        const int isI = kc >> 4;
        int sidx;
        if (dir == 0) sidx = (q*9 + p)*256 + ci*16 + co;          // Wf[co,ci,p,q]=K[q,p,ci,co]
        else          sidx = ((8-q)*9 + (8-p))*256 + co*16 + ci;  // Wb = conj flip swap
        const float wr = kr[sidx];
        const float wi = (dir == 0) ? ki[sidx] : -ki[sidx];
        vv[t] = (hf == 0) ? (isI ? -wi : wr) : (isI ? wr : wi);
    }
    u32 pk[4];
    #pragma unroll
    for (int t = 0; t < 4; ++t) pk[t] = bf16rn(vv[2*t]) | (bf16rn(vv[2*t+1]) << 16);
    u32* o = wbuf + (size_t)(dir*162 + (q*9 + p)*2 + hf)*256 + lane*4;
    *(uint4*)o = make_uint4(pk[0], pk[1], pk[2], pk[3]);
}

__global__ void prep_fields(const float* __restrict__ ks, const float* __restrict__ prev,
                            float2* __restrict__ wsf, uint8_t* __restrict__ mask8) {
    const int pix = blockIdx.x * blockDim.x + threadIdx.x;
    if (pix >= NPIX) return;
    #pragma unroll
    for (int c = 0; c < 16; ++c) {
        const float krr = ks[(size_t)pix*32 + c];
        const float kii = ks[(size_t)pix*32 + c + 16];
        mask8[(size_t)c*NPIX + pix] = (krr != 0.f || kii != 0.f) ? 1 : 0;
        wsf[(size_t)c*NPIX + pix] = make_float2(prev[(size_t)pix*32 + c], prev[(size_t)pix*32 + c + 16]);
    }
}

// MODE 0: out = conv(x) - x
// MODE 1: out = conv(x) - x + (mask+am)*aux ; partial += out*conj(aux)
// MODE 2: out=out2 = mask*kk + am*z - (conv(x)-x) - (mask+am)*aux ; partial += |out|^2
// Each wave handles ONE component (hf); all epilogue math is separable.
template<int MODE>
__global__ __launch_bounds__(384)
void conv9(const float2* __restrict__ x, const u32* __restrict__ Wd,
           float2* __restrict__ out, float2* __restrict__ out2,
           const float2* __restrict__ aux, const float* __restrict__ ks,
           const float* __restrict__ z, const uint8_t* __restrict__ mask8,
           const float* __restrict__ miu, float2* __restrict__ partials)
{
    __shared__ __align__(16) char Xs[20*24*64];   // 30720 B -> 3 blocks/CU easily
    const int t = threadIdx.x;
    const int bi = blockIdx.x;
    const int i0 = (bi / 24) * 12;    // 32 row tiles of 12 rows
    const int j0 = (bi % 24) * 16;    // 24 col tiles of 16 cols
    const int w = t >> 6, lane = t & 63;
    const int hf = (w >= 3) ? 1 : 0;  // 0: real component, 1: imag component
    const int wr = w - 3*hf;          // row group (rows 4wr..4wr+3)
    const int m = lane & 15, g = lane >> 4;

    // ---- stage 20x24 slab (rows i0-4..i0+15, cols j0-4..j0+19), bf16 RN,
    //      64 B/px: 4 slots of 16B, content c stored at slot c ^ (col&3).
    for (int u = t; u < 20*24; u += 384) {
        const int col = u % 24, row = u / 24;
        const int row_g = i0 - 4 + row, col_g = j0 - 4 + col;
        const bool valid = ((unsigned)row_g < MM) && ((unsigned)col_g < MM);
        const float2* src = x + (size_t)row_g*MM + col_g;
        float2 v[16];
        #pragma unroll
        for (int ci = 0; ci < 16; ++ci)
            v[ci] = valid ? src[(size_t)ci*NPIX] : make_float2(0.f, 0.f);
        u32 c0[4], c1[4], c2[4], c3[4];
        #pragma unroll
        for (int j = 0; j < 4; ++j) {
            c0[j] = bf16rn(v[2*j].x)     | (bf16rn(v[2*j+1].x) << 16);
            c1[j] = bf16rn(v[8+2*j].x)   | (bf16rn(v[9+2*j].x) << 16);
            c2[j] = bf16rn(v[2*j].y)     | (bf16rn(v[2*j+1].y) << 16);
            c3[j] = bf16rn(v[8+2*j].y)   | (bf16rn(v[9+2*j].y) << 16);
        }
        const int k3 = col & 3;
        char* pb = Xs + (size_t)(row*24 + col)*64;
        *(uint4*)(pb + (((0 ^ k3)) << 4)) = make_uint4(c0[0], c0[1], c0[2], c0[3]);
        *(uint4*)(pb + (((1 ^ k3)) << 4)) = make_uint4(c1[0], c1[1], c1[2], c1[3]);
        *(uint4*)(pb + (((2 ^ k3)) << 4)) = make_uint4(c2[0], c2[1], c2[2], c2[3]);
        *(uint4*)(pb + (((3 ^ k3)) << 4)) = make_uint4(c3[0], c3[1], c3[2], c3[3]);
    }
    __syncthreads();

    f32x4 acc[4];
    #pragma unroll
    for (int a = 0; a < 4; ++a) acc[a] = (f32x4){0.f, 0.f, 0.f, 0.f};

    // ---- 81 taps, q-outer / p-inner (unrolled 9). Wave owns output rows
    //      4wr..4wr+3, component hf; tap p uses slab rows 4wr+p..4wr+p+3 ->
    //      rotate X0..X4. W ring WA/WB/WC (1 frag each, this wave's hf);
    //      tap (q,p) uses slot p%3; COMPUTE THEN PREFETCH (R8 bug reversed).
    const char* wl = (const char*)Wd + (lane << 4) + (hf << 10);
    short8 WA, WB, WC;

    #define LW(WS, ADDR) do { WS = *(const short8*)(ADDR); } while (0)

    #define MFQ(Xa, Xb, Xc, Xd, WS) do { \
        acc[0] = __builtin_amdgcn_mfma_f32_16x16x32_bf16(WS, Xa, acc[0], 0, 0, 0); \
        acc[1] = __builtin_amdgcn_mfma_f32_16x16x32_bf16(WS, Xb, acc[1], 0, 0, 0); \
        acc[2] = __builtin_amdgcn_mfma_f32_16x16x32_bf16(WS, Xc, acc[2], 0, 0, 0); \
        acc[3] = __builtin_amdgcn_mfma_f32_16x16x32_bf16(WS, Xd, acc[3], 0, 0, 0); } while (0)

    LW(WA, wl);            // (q0,p0)
    LW(WB, wl + 2048);     // (q0,p1)
    LW(WC, wl + 4096);     // (q0,p2)

    #pragma unroll 1
    for (int qq = 0; qq < 9; ++qq) {
        const char* wq = wl + (size_t)qq * 18432;
        const int colq = m + qq;
        const char* xb = Xs + (size_t)((4*wr)*24 + colq)*64 + ((g ^ (colq & 3)) << 4);
        short8 X0 = *(const short8*)(xb);
        short8 X1 = *(const short8*)(xb + 1536);
        short8 X2 = *(const short8*)(xb + 2*1536);
        short8 X3 = *(const short8*)(xb + 3*1536);
        short8 X4;
        // compute tap (qq,p) with ring slot p%3, THEN prefetch tap (qq,p+3)
        X4 = *(const short8*)(xb + 4*1536);  MFQ(X0, X1, X2, X3, WA); LW(WA, wq + 3*2048);   // p0
        X0 = *(const short8*)(xb + 5*1536);  MFQ(X1, X2, X3, X4, WB); LW(WB, wq + 4*2048);   // p1
        X1 = *(const short8*)(xb + 6*1536);  MFQ(X2, X3, X4, X0, WC); LW(WC, wq + 5*2048);   // p2
        X2 = *(const short8*)(xb + 7*1536);  MFQ(X3, X4, X0, X1, WA); LW(WA, wq + 6*2048);   // p3
        X3 = *(const short8*)(xb + 8*1536);  MFQ(X4, X0, X1, X2, WB); LW(WB, wq + 7*2048);   // p4
        X4 = *(const short8*)(xb + 9*1536);  MFQ(X0, X1, X2, X3, WC); LW(WC, wq + 8*2048);   // p5
        X0 = *(const short8*)(xb + 10*1536); MFQ(X1, X2, X3, X4, WA); LW(WA, wq + 9*2048);   // p6 ; pf (q+1,p0)
        X1 = *(const short8*)(xb + 11*1536); MFQ(X2, X3, X4, X0, WB); LW(WB, wq + 10*2048);  // p7 ; pf (q+1,p1)
                                             MFQ(X3, X4, X0, X1, WC); LW(WC, wq + 11*2048); // p8 ; pf (q+1,p2)
    }
    #undef LW
    #undef MFQ
    // (last column's prefetches over-read a few KB past this dir's W region;
    //  values unused, addresses stay inside d_ws — harmless.)

    // ---- epilogue: C/D col = lane&15 = pixel col, row = g*4+j = co.
    //      This wave stores only component hf of each float2; cross-component
    //      dot terms are separable and summed in the block reduction.
    const float am = (MODE >= 1) ? fabsf(miu[0]) : 0.f;
    float2 part = make_float2(0.f, 0.f);
    const float* xf  = (const float*)x;
    const float* axf = (const float*)aux;
    float* of  = (float*)out;
    float* o2f = (float*)out2;
    #pragma unroll
    for (int r = 0; r < 4; ++r) {
        const int rowo = i0 + 4*wr + r;
        const int colo = j0 + m;
        const int pix = rowo*MM + colo;
        #pragma unroll
        for (int j = 0; j < 4; ++j) {
            const int co = g*4 + j;
            const size_t idx = (size_t)co*NPIX + pix;
            const float v = acc[r][j];
            if (MODE == 0) {
                of[2*idx + hf] = v - xf[2*idx + hf];
            } else if (MODE == 1) {
                const float tc = xf[2*idx + hf];
                const float2 pc = aux[idx];
                const float pc_c = hf ? pc.y : pc.x;
                const float mv = mask8[idx] ? 1.f : 0.f;
                const float qc = v - tc + (mv + am)*pc_c;
                of[2*idx + hf] = qc;
                // part = sum q*conj(p): re += qr*pr + qi*pi ; im += qi*pr - qr*pi
                part.x += qc * pc_c;
                part.y += hf ? qc * pc.x : -qc * pc.y;
            } else {
                const float tc = xf[2*idx + hf];
                const float wc = axf[2*idx + hf];
                const float mv = mask8[idx] ? 1.f : 0.f;
                const float kc = ks[(size_t)pix*32 + co + 16*hf];
                const float zc = z[(size_t)pix*32 + co + 16*hf];
                const float pc = mv*kc + am*zc - (v - tc) - (mv + am)*wc;
                of[2*idx + hf]  = pc;
                o2f[2*idx + hf] = pc;
                part.x += pc * pc;
            }
        }
    }
    if (MODE >= 1) {
        __syncthreads();
        part = block_reduce2(part);
        if (t == 0) partials[bi] = part;
    }
}

__global__ void finalize_rr(const float2* __restrict__ partials, float* __restrict__ scal, int n) {
    float2 s = make_float2(0.f, 0.f);
    for (int i = threadIdx.x; i < n; i += blockDim.x) { s.x += partials[i].x; s.y += partials[i].y; }
    s = block_reduce2(s);
    if (threadIdx.x == 0) scal[0] = s.x;
}

__global__ void finalize_alpha(const float2* __restrict__ partials, float* __restrict__ scal, int n) {
    float2 s = make_float2(0.f, 0.f);
    for (int i = threadIdx.x; i < n; i += blockDim.x) { s.x += partials[i].x; s.y += partials[i].y; }
    s = block_reduce2(s);
    if (threadIdx.x == 0) {
        const float rr = scal[0];
        const float d = s.x*s.x + s.y*s.y;
        scal[1] =  rr * s.x / d;
        scal[2] = -rr * s.y / d;
    }
}

// r -= alpha*q ; partial += |r|^2
__global__ void update_r(float2* __restrict__ r, const float2* __restrict__ q,
                         const float* __restrict__ scal, float2* __restrict__ partials) {
    const float ar = scal[1], ai = scal[2];
    float2 s = make_float2(0.f, 0.f);
    for (int e = blockIdx.x*256 + threadIdx.x; e < N2; e += NRED*256) {
        const float2 qv = q[e];
        float2 rv = r[e];
        rv.x -= ar*qv.x - ai*qv.y;
        rv.y -= ar*qv.y + ai*qv.x;
        r[e] = rv;
        s.x += rv.x*rv.x + rv.y*rv.y;
    }
    s = block_reduce2(s);
    if (threadIdx.x == 0) partials[blockIdx.x] = s;
}

__global__ void finalize_beta(const float2* __restrict__ partials, float* __restrict__ scal) {
    float2 v = partials[threadIdx.x];
    v = block_reduce2(v);
    if (threadIdx.x == 0) {
        const float rn = v.x;
        scal[3] = rn / scal[0];
        scal[0] = rn;
    }
}

// b += alpha*p_old ; p = r + beta*p_old   (alpha from this iter, beta just computed)
__global__ void update_pb(float2* __restrict__ p, const float2* __restrict__ r,
                          float2* __restrict__ b, const float* __restrict__ scal) {
    const float ar = scal[1], ai = scal[2], beta = scal[3];
    const int e = blockIdx.x*256 + threadIdx.x;
    if (e < N2) {
        const float2 pv = p[e], rv = r[e];
        float2 bv = b[e];
        bv.x += ar*pv.x - ai*pv.y;
        bv.y += ar*pv.y + ai*pv.x;
        b[e] = bv;
        p[e] = make_float2(rv.x + beta*pv.x, rv.y + beta*pv.y);
    }
}

__global__ void pack_out(const float2* __restrict__ b, float* __restrict__ out) {
    const int e = blockIdx.x*256 + threadIdx.x;
    if (e >= 32*NPIX) return;
    const int pix = e >> 5;
    const int cc  = e & 31;
    const float2 v = b[(size_t)(cc & 15)*NPIX + pix];
    out[e] = (cc < 16) ? v.x : v.y;
}

extern "C" void kernel_launch(void* const* d_in, const int* in_sizes, int n_in,
                              void* d_out, int out_size, void* d_ws, size_t ws_size,
                              hipStream_t stream) {
    const float* z    = (const float*)d_in[0];
    const float* ks   = (const float*)d_in[1];
    const float* kr   = (const float*)d_in[2];
    const float* ki   = (const float*)d_in[3];
    const float* prev = (const float*)d_in[5];
    const float* miu  = (const float*)d_in[6];
    float* out = (float*)d_out;

    char* w = (char*)d_ws;
    const size_t FB = (size_t)N2 * sizeof(float2);
    float2* wsf = (float2*)w; w += FB;    // b (in-place)
    float2* pf  = (float2*)w; w += FB;
    float2* rf  = (float2*)w; w += FB;
    float2* qf  = (float2*)w; w += FB;
    float2* tf  = (float2*)w; w += FB;
    u32* wbuf   = (u32*)w;   w += (size_t)2*162*256*sizeof(u32);   // 331776 B
    uint8_t* mask8 = (uint8_t*)w; w += (size_t)N2;
    w = (char*)(((uintptr_t)w + 255) & ~(uintptr_t)255);
    float2* partials = (float2*)w; w += (size_t)NCBLK * sizeof(float2);
    float*  scal     = (float*)w;

    const u32* wbF = wbuf;
    const u32* wbB = wbuf + (size_t)162*256;

    prep_weights<<<81, 256, 0, stream>>>(kr, ki, wbuf);
    prep_fields<<<576, 256, 0, stream>>>(ks, prev, wsf, mask8);

    conv9<0><<<NCBLK, 384, 0, stream>>>(wsf, wbF, tf, nullptr, nullptr, nullptr, nullptr, nullptr, nullptr, nullptr);
    conv9<2><<<NCBLK, 384, 0, stream>>>(tf, wbB, pf, rf, wsf, ks, z, mask8, miu, partials);
    finalize_rr<<<1, 256, 0, stream>>>(partials, scal, NCBLK);

    for (int it = 0; it < 10; ++it) {
        conv9<0><<<NCBLK, 384, 0, stream>>>(pf, wbF, tf, nullptr, nullptr, nullptr, nullptr, nullptr, nullptr, nullptr);
        conv9<1><<<NCBLK, 384, 0, stream>>>(tf, wbB, qf, nullptr, pf, nullptr, nullptr, mask8, miu, partials);
        finalize_alpha<<<1, 256, 0, stream>>>(partials, scal, NCBLK);
        update_r<<<NRED, 256, 0, stream>>>(rf, qf, scal, partials);
        finalize_beta<<<1, NRED, 0, stream>>>(partials, scal);
        update_pb<<<9216, 256, 0, stream>>>(pf, rf, wsf, scal);
    }

    pack_out<<<18432, 256, 0, stream>>>(wsf, out);
}

// Round 12
// 1022.586 us; speedup vs baseline: 2.3073x; 1.1177x over previous
//
#include <hip/hip_runtime.h>
#include <stdint.h>

// SPIRiT CG reconstruction. Convs: single-product bf16 MFMA (W and X RN bf16),
// per-tap implicit GEMM M=16 c_out, N=16 pixels, K=32 = 16 c_in x {re,im}.
// Conv kernel: 12x16 tile, 384 threads (6 waves = 2 components x 3 row-groups),
// grid 768 = 3 blocks/CU, XCD-swizzled (4-tile-row band per XCD -> band working
// set 2.75 MB fits the 4 MB XCD L2). Deep register pipelining: X ring-6 with
// 2-tap slack + cross-column tail loads; W ring-9 (full-column prefetch,
// phase-invariant since 9 taps/column). Compute-then-prefetch ordering.

#define MM 384
#define NPIX (MM*MM)          // 147456
#define N2 (16*NPIX)
#define NRED 512
#define NCBLK 768             // 32 row-tiles (12 rows) x 24 col-tiles (16 cols)

typedef __attribute__((ext_vector_type(8))) short short8;
typedef __attribute__((ext_vector_type(4))) float f32x4;
typedef unsigned int u32;

__device__ __forceinline__ float2 block_reduce2(float2 v) {
    #pragma unroll
    for (int off = 32; off > 0; off >>= 1) {
        v.x += __shfl_down(v.x, off);
        v.y += __shfl_down(v.y, off);
    }
    __shared__ float2 tmp[8];
    const int wid = threadIdx.x >> 6, lid = threadIdx.x & 63;
    if (lid == 0) tmp[wid] = v;
    __syncthreads();
    if (threadIdx.x == 0) {
        const int nw = blockDim.x >> 6;
        for (int i = 1; i < nw; ++i) { v.x += tmp[i].x; v.y += tmp[i].y; }
    }
    return v;
}

__device__ __forceinline__ u32 bf16rn(float f) {   // round-to-nearest-even bf16
    const u32 u = __float_as_uint(f);
    return (u + 0x7FFFu + ((u >> 16) & 1u)) >> 16;
}

// Weight fragments (RN bf16): [dir][slot=q*9+p][hf][lane64][4 u32]  (q-major)
// hf=0 rows: [Wr | -Wi] (-> real), hf=1 rows: [Wi | Wr] (-> imag);
// lane = co + 16*kgroup. Tap block = 2 KB (1 KB per hf).
__global__ void prep_weights(const float* __restrict__ kr, const float* __restrict__ ki,
                             u32* __restrict__ wbuf) {
    const int e = blockIdx.x * 256 + threadIdx.x;
    if (e >= 20736) return;    // 2 dir x 81 tap x 2 hf x 64 lane
    const int lane = e & 63;
    int r = e >> 6;
    const int hf = r & 1; r >>= 1;
    const int q = r % 9; r /= 9;
    const int p = r % 9; r /= 9;
    const int dir = r;
    const int co = lane & 15, g = lane >> 4;
    float vv[8];
    #pragma unroll
    for (int t = 0; t < 8; ++t) {
        const int kc = 8 * g + t;
        const int ci = kc & 15;
        const int isI = kc >> 4;
        int sidx;
        if (dir == 0) sidx = (q*9 + p)*256 + ci*16 + co;          // Wf[co,ci,p,q]=K[q,p,ci,co]
        else          sidx = ((8-q)*9 + (8-p))*256 + co*16 + ci;  // Wb = conj flip swap
        const float wr = kr[sidx];
        const float wi = (dir == 0) ? ki[sidx] : -ki[sidx];
        vv[t] = (hf == 0) ? (isI ? -wi : wr) : (isI ? wr : wi);
    }
    u32 pk[4];
    #pragma unroll
    for (int t = 0; t < 4; ++t) pk[t] = bf16rn(vv[2*t]) | (bf16rn(vv[2*t+1]) << 16);
    u32* o = wbuf + (size_t)(dir*162 + (q*9 + p)*2 + hf)*256 + lane*4;
    *(uint4*)o = make_uint4(pk[0], pk[1], pk[2], pk[3]);
}

__global__ void prep_fields(const float* __restrict__ ks, const float* __restrict__ prev,
                            float2* __restrict__ wsf, uint8_t* __restrict__ mask8) {
    const int pix = blockIdx.x * blockDim.x + threadIdx.x;
    if (pix >= NPIX) return;
    #pragma unroll
    for (int c = 0; c < 16; ++c) {
        const float krr = ks[(size_t)pix*32 + c];
        const float kii = ks[(size_t)pix*32 + c + 16];
        mask8[(size_t)c*NPIX + pix] = (krr != 0.f || kii != 0.f) ? 1 : 0;
        wsf[(size_t)c*NPIX + pix] = make_float2(prev[(size_t)pix*32 + c], prev[(size_t)pix*32 + c + 16]);
    }
}

// MODE 0: out = conv(x) - x
// MODE 1: out = conv(x) - x + (mask+am)*aux ; partial += out*conj(aux)
// MODE 2: out=out2 = mask*kk + am*z - (conv(x)-x) - (mask+am)*aux ; partial += |out|^2
// Each wave handles ONE component (hf); all epilogue math is separable.
template<int MODE>
__global__ __launch_bounds__(384, 5)
void conv9(const float2* __restrict__ x, const u32* __restrict__ Wd,
           float2* __restrict__ out, float2* __restrict__ out2,
           const float2* __restrict__ aux, const float* __restrict__ ks,
           const float* __restrict__ z, const uint8_t* __restrict__ mask8,
           const float* __restrict__ miu, float2* __restrict__ partials)
{
    __shared__ __align__(16) char Xs[20*24*64];   // 30720 B
    const int t = threadIdx.x;
    const int bi0 = blockIdx.x;
    const int bi = (bi0 & 7) * 96 + (bi0 >> 3);   // XCD swizzle: 4-tile-row band/XCD
    const int i0 = (bi / 24) * 12;
    const int j0 = (bi % 24) * 16;
    const int w = t >> 6, lane = t & 63;
    const int hf = (w >= 3) ? 1 : 0;  // 0: real component, 1: imag component
    const int wr = w - 3*hf;          // row group (rows 4wr..4wr+3)
    const int m = lane & 15, g = lane >> 4;

    // ---- stage 20x24 slab (rows i0-4..i0+15, cols j0-4..j0+19), bf16 RN,
    //      64 B/px: 4 slots of 16B, content c stored at slot c ^ (col&3).
    for (int u = t; u < 20*24; u += 384) {
        const int col = u % 24, row = u / 24;
        const int row_g = i0 - 4 + row, col_g = j0 - 4 + col;
        const bool valid = ((unsigned)row_g < MM) && ((unsigned)col_g < MM);
        const float2* src = x + (size_t)row_g*MM + col_g;
        float2 v[16];
        #pragma unroll
        for (int ci = 0; ci < 16; ++ci)
            v[ci] = valid ? src[(size_t)ci*NPIX] : make_float2(0.f, 0.f);
        u32 c0[4], c1[4], c2[4], c3[4];
        #pragma unroll
        for (int j = 0; j < 4; ++j) {
            c0[j] = bf16rn(v[2*j].x)     | (bf16rn(v[2*j+1].x) << 16);
            c1[j] = bf16rn(v[8+2*j].x)   | (bf16rn(v[9+2*j].x) << 16);
            c2[j] = bf16rn(v[2*j].y)     | (bf16rn(v[2*j+1].y) << 16);
            c3[j] = bf16rn(v[8+2*j].y)   | (bf16rn(v[9+2*j].y) << 16);
        }
        const int k3 = col & 3;
        char* pb = Xs + (size_t)(row*24 + col)*64;
        *(uint4*)(pb + (((0 ^ k3)) << 4)) = make_uint4(c0[0], c0[1], c0[2], c0[3]);
        *(uint4*)(pb + (((1 ^ k3)) << 4)) = make_uint4(c1[0], c1[1], c1[2], c1[3]);
        *(uint4*)(pb + (((2 ^ k3)) << 4)) = make_uint4(c2[0], c2[1], c2[2], c2[3]);
        *(uint4*)(pb + (((3 ^ k3)) << 4)) = make_uint4(c3[0], c3[1], c3[2], c3[3]);
    }
    __syncthreads();

    f32x4 acc[4];
    #pragma unroll
    for (int a = 0; a < 4; ++a) acc[a] = (f32x4){0.f, 0.f, 0.f, 0.f};

    // ---- 81 taps, q-outer / p-inner (unrolled 9). Wave owns output rows
    //      4wr..4wr+3, component hf. X ring-6 (rows r -> X[r%6], loads 2 taps
    //      ahead of first use; column tail preloads next column rows 0..4).
    //      W ring-9: tap p uses W[p]; after use, prefetch next column's tap p
    //      (9-tap slack). COMPUTE THEN PREFETCH throughout.
    const char* wl = (const char*)Wd + (lane << 4) + (hf << 10);
    short8 W0, W1, W2, W3, W4, W5, W6, W7, W8;
    short8 X0, X1, X2, X3, X4, X5;

    #define LW(WS, ADDR) do { WS = *(const short8*)(ADDR); } while (0)
    #define MFQ(Xa, Xb, Xc, Xd, WS) do { \
        acc[0] = __builtin_amdgcn_mfma_f32_16x16x32_bf16(WS, Xa, acc[0], 0, 0, 0); \
        acc[1] = __builtin_amdgcn_mfma_f32_16x16x32_bf16(WS, Xb, acc[1], 0, 0, 0); \
        acc[2] = __builtin_amdgcn_mfma_f32_16x16x32_bf16(WS, Xc, acc[2], 0, 0, 0); \
        acc[3] = __builtin_amdgcn_mfma_f32_16x16x32_bf16(WS, Xd, acc[3], 0, 0, 0); } while (0)

    // preamble: column 0 weights (taps 0..8) and X rows 0..4
    LW(W0, wl);            LW(W1, wl + 2048);   LW(W2, wl + 4096);
    LW(W3, wl + 6144);     LW(W4, wl + 8192);   LW(W5, wl + 10240);
    LW(W6, wl + 12288);    LW(W7, wl + 14336);  LW(W8, wl + 16384);
    {
        const char* xb0 = Xs + (size_t)((4*wr)*24 + m)*64 + ((g ^ (m & 3)) << 4);
        X0 = *(const short8*)(xb0);
        X1 = *(const short8*)(xb0 + 1536);
        X2 = *(const short8*)(xb0 + 2*1536);
        X3 = *(const short8*)(xb0 + 3*1536);
        X4 = *(const short8*)(xb0 + 4*1536);
    }

    #pragma unroll 1
    for (int qq = 0; qq < 9; ++qq) {
        const char* wq = wl + (size_t)qq * 18432 + 18432;   // next column taps
        const int colq = m + qq;
        const char* xb  = Xs + (size_t)((4*wr)*24 + colq)*64 + ((g ^ (colq & 3)) << 4);
        const int colq1 = colq + 1;
        const char* xbn = Xs + (size_t)((4*wr)*24 + colq1)*64 + ((g ^ (colq1 & 3)) << 4);

        MFQ(X0, X1, X2, X3, W0); LW(W0, wq);           X5 = *(const short8*)(xb + 5*1536);   // p0
        MFQ(X1, X2, X3, X4, W1); LW(W1, wq + 2048);    X0 = *(const short8*)(xb + 6*1536);   // p1
        MFQ(X2, X3, X4, X5, W2); LW(W2, wq + 4096);    X1 = *(const short8*)(xb + 7*1536);   // p2
        MFQ(X3, X4, X5, X0, W3); LW(W3, wq + 6144);    X2 = *(const short8*)(xb + 8*1536);   // p3
        MFQ(X4, X5, X0, X1, W4); LW(W4, wq + 8192);    X3 = *(const short8*)(xb + 9*1536);   // p4
        MFQ(X5, X0, X1, X2, W5); LW(W5, wq + 10240);   X4 = *(const short8*)(xb + 10*1536);  // p5
        MFQ(X0, X1, X2, X3, W6); LW(W6, wq + 12288);   X5 = *(const short8*)(xb + 11*1536);  // p6
        MFQ(X1, X2, X3, X4, W7); LW(W7, wq + 14336);   X0 = *(const short8*)(xbn);           // p7
        MFQ(X2, X3, X4, X5, W8); LW(W8, wq + 16384);   X1 = *(const short8*)(xbn + 1536);    // p8
        X2 = *(const short8*)(xbn + 2*1536);
        X3 = *(const short8*)(xbn + 3*1536);
        X4 = *(const short8*)(xbn + 4*1536);
    }
    #undef LW
    #undef MFQ
    // (last column's W prefetches over-read ~20 KB past this dir's W region
    //  into later d_ws buffers; X tail reads stay inside Xs. Values unused.)

    // ---- epilogue: C/D col = lane&15 = pixel col, row = g*4+j = co.
    //      This wave stores only component hf of each float2; cross-component
    //      dot terms are separable and summed in the block reduction.
    const float am = (MODE >= 1) ? fabsf(miu[0]) : 0.f;
    float2 part = make_float2(0.f, 0.f);
    const float* xf  = (const float*)x;
    const float* axf = (const float*)aux;
    float* of  = (float*)out;
    float* o2f = (float*)out2;
    #pragma unroll
    for (int r = 0; r < 4; ++r) {
        const int rowo = i0 + 4*wr + r;
        const int colo = j0 + m;
        const int pix = rowo*MM + colo;
        #pragma unroll
        for (int j = 0; j < 4; ++j) {
            const int co = g*4 + j;
            const size_t idx = (size_t)co*NPIX + pix;
            const float v = acc[r][j];
            if (MODE == 0) {
                of[2*idx + hf] = v - xf[2*idx + hf];
            } else if (MODE == 1) {
                const float tc = xf[2*idx + hf];
                const float2 pc = aux[idx];
                const float pc_c = hf ? pc.y : pc.x;
                const float mv = mask8[idx] ? 1.f : 0.f;
                const float qc = v - tc + (mv + am)*pc_c;
                of[2*idx + hf] = qc;
                part.x += qc * pc_c;
                part.y += hf ? qc * pc.x : -qc * pc.y;
            } else {
                const float tc = xf[2*idx + hf];
                const float wc = axf[2*idx + hf];
                const float mv = mask8[idx] ? 1.f : 0.f;
                const float kc = ks[(size_t)pix*32 + co + 16*hf];
                const float zc = z[(size_t)pix*32 + co + 16*hf];
                const float pc = mv*kc + am*zc - (v - tc) - (mv + am)*wc;
                of[2*idx + hf]  = pc;
                o2f[2*idx + hf] = pc;
                part.x += pc * pc;
            }
        }
    }
    if (MODE >= 1) {
        __syncthreads();
        part = block_reduce2(part);
        if (t == 0) partials[bi] = part;
    }
}

__global__ void finalize_rr(const float2* __restrict__ partials, float* __restrict__ scal, int n) {
    float2 s = make_float2(0.f, 0.f);
    for (int i = threadIdx.x; i < n; i += blockDim.x) { s.x += partials[i].x; s.y += partials[i].y; }
    s = block_reduce2(s);
    if (threadIdx.x == 0) scal[0] = s.x;
}

__global__ void finalize_alpha(const float2* __restrict__ partials, float* __restrict__ scal, int n) {
    float2 s = make_float2(0.f, 0.f);
    for (int i = threadIdx.x; i < n; i += blockDim.x) { s.x += partials[i].x; s.y += partials[i].y; }
    s = block_reduce2(s);
    if (threadIdx.x == 0) {
        const float rr = scal[0];
        const float d = s.x*s.x + s.y*s.y;
        scal[1] =  rr * s.x / d;
        scal[2] = -rr * s.y / d;
    }
}

// r -= alpha*q ; partial += |r|^2
__global__ void update_r(float2* __restrict__ r, const float2* __restrict__ q,
                         const float* __restrict__ scal, float2* __restrict__ partials) {
    const float ar = scal[1], ai = scal[2];
    float2 s = make_float2(0.f, 0.f);
    for (int e = blockIdx.x*256 + threadIdx.x; e < N2; e += NRED*256) {
        const float2 qv = q[e];
        float2 rv = r[e];
        rv.x -= ar*qv.x - ai*qv.y;
        rv.y -= ar*qv.y + ai*qv.x;
        r[e] = rv;
        s.x += rv.x*rv.x + rv.y*rv.y;
    }
    s = block_reduce2(s);
    if (threadIdx.x == 0) partials[blockIdx.x] = s;
}

__global__ void finalize_beta(const float2* __restrict__ partials, float* __restrict__ scal) {
    float2 v = partials[threadIdx.x];
    v = block_reduce2(v);
    if (threadIdx.x == 0) {
        const float rn = v.x;
        scal[3] = rn / scal[0];
        scal[0] = rn;
    }
}

// b += alpha*p_old ; p = r + beta*p_old
__global__ void update_pb(float2* __restrict__ p, const float2* __restrict__ r,
                          float2* __restrict__ b, const float* __restrict__ scal) {
    const float ar = scal[1], ai = scal[2], beta = scal[3];
    const int e = blockIdx.x*256 + threadIdx.x;
    if (e < N2) {
        const float2 pv = p[e], rv = r[e];
        float2 bv = b[e];
        bv.x += ar*pv.x - ai*pv.y;
        bv.y += ar*pv.y + ai*pv.x;
        b[e] = bv;
        p[e] = make_float2(rv.x + beta*pv.x, rv.y + beta*pv.y);
    }
}

// final iteration: only b += alpha*p is live
__global__ void update_bfinal(float2* __restrict__ b, const float2* __restrict__ p,
                              const float* __restrict__ scal) {
    const float ar = scal[1], ai = scal[2];
    const int e = blockIdx.x*256 + threadIdx.x;
    if (e < N2) {
        const float2 pv = p[e];
        float2 bv = b[e];
        bv.x += ar*pv.x - ai*pv.y;
        bv.y += ar*pv.y + ai*pv.x;
        b[e] = bv;
    }
}

__global__ void pack_out(const float2* __restrict__ b, float* __restrict__ out) {
    const int e = blockIdx.x*256 + threadIdx.x;
    if (e >= 32*NPIX) return;
    const int pix = e >> 5;
    const int cc  = e & 31;
    const float2 v = b[(size_t)(cc & 15)*NPIX + pix];
    out[e] = (cc < 16) ? v.x : v.y;
}

extern "C" void kernel_launch(void* const* d_in, const int* in_sizes, int n_in,
                              void* d_out, int out_size, void* d_ws, size_t ws_size,
                              hipStream_t stream) {
    const float* z    = (const float*)d_in[0];
    const float* ks   = (const float*)d_in[1];
    const float* kr   = (const float*)d_in[2];
    const float* ki   = (const float*)d_in[3];
    const float* prev = (const float*)d_in[5];
    const float* miu  = (const float*)d_in[6];
    float* out = (float*)d_out;

    char* w = (char*)d_ws;
    const size_t FB = (size_t)N2 * sizeof(float2);
    float2* wsf = (float2*)w; w += FB;    // b (in-place)
    float2* pf  = (float2*)w; w += FB;
    float2* rf  = (float2*)w; w += FB;
    float2* qf  = (float2*)w; w += FB;
    float2* tf  = (float2*)w; w += FB;
    u32* wbuf   = (u32*)w;   w += (size_t)2*162*256*sizeof(u32);   // 331776 B
    uint8_t* mask8 = (uint8_t*)w; w += (size_t)N2;
    w = (char*)(((uintptr_t)w + 255) & ~(uintptr_t)255);
    float2* partials = (float2*)w; w += (size_t)NCBLK * sizeof(float2);
    float*  scal     = (float*)w;

    const u32* wbF = wbuf;
    const u32* wbB = wbuf + (size_t)162*256;

    prep_weights<<<81, 256, 0, stream>>>(kr, ki, wbuf);
    prep_fields<<<576, 256, 0, stream>>>(ks, prev, wsf, mask8);

    conv9<0><<<NCBLK, 384, 0, stream>>>(wsf, wbF, tf, nullptr, nullptr, nullptr, nullptr, nullptr, nullptr, nullptr);
    conv9<2><<<NCBLK, 384, 0, stream>>>(tf, wbB, pf, rf, wsf, ks, z, mask8, miu, partials);
    finalize_rr<<<1, 256, 0, stream>>>(partials, scal, NCBLK);

    for (int it = 0; it < 10; ++it) {
        conv9<0><<<NCBLK, 384, 0, stream>>>(pf, wbF, tf, nullptr, nullptr, nullptr, nullptr, nullptr, nullptr, nullptr);
        conv9<1><<<NCBLK, 384, 0, stream>>>(tf, wbB, qf, nullptr, pf, nullptr, nullptr, mask8, miu, partials);
        finalize_alpha<<<1, 256, 0, stream>>>(partials, scal, NCBLK);
        if (it < 9) {
            update_r<<<NRED, 256, 0, stream>>>(rf, qf, scal, partials);
            finalize_beta<<<1, NRED, 0, stream>>>(partials, scal);
            update_pb<<<9216, 256, 0, stream>>>(pf, rf, wsf, scal);
        } else {
            update_bfinal<<<9216, 256, 0, stream>>>(wsf, pf, scal);
        }
    }

    pack_out<<<18432, 256, 0, stream>>>(wsf, out);
}